// Round 4
// baseline (2790.470 us; speedup 1.0000x reference)
//
#include <hip/hip_runtime.h>
#include <hip/hip_bf16.h>
#include <math.h>

// Problem constants
#define BATCH 4
#define CDIM 192
#define HDIM 224
#define WDIM 224
#define HWSZ (HDIM * WDIM)            // 50176
#define NWH 28                        // 224/8
#define NWIN (BATCH * NWH * NWH)      // 3136
#define TOK 64
#define MTOK (NWIN * TOK)             // 200704
#define HEADS 6
#define C3 (3 * CDIM)                 // 576
#define C4 (4 * CDIM)                 // 768
#define IMGSZ (BATCH * CDIM * HWSZ)   // 38535168
#define ATTN_SCALE 0.17677669529663687f
#define LN_EPS 1e-6f
#define PBP 200                        // pb row pitch (ushorts), 400 B, 16B-aligned

typedef __attribute__((ext_vector_type(8))) short bfrag;   // 8 bf16 (4 VGPRs)
typedef __attribute__((ext_vector_type(4))) float f32x4;

__device__ __forceinline__ float bf2f(unsigned short u) {
    union { unsigned int i; float f; } v; v.i = ((unsigned int)u) << 16; return v.f;
}
__device__ __forceinline__ unsigned short f2bf(float f) {
    union { unsigned int i; float f; } v; v.f = f;
    unsigned int r = (v.i + 0x7FFFu + ((v.i >> 16) & 1u)) >> 16;   // RNE
    return (unsigned short)r;
}
// exact-erf GELU via Abramowitz-Stegun 7.1.26 (|erf err| <= 1.5e-7)
__device__ __forceinline__ float gelu_erf(float x) {
    float z = fabsf(x) * 0.70710678118654752f;
    float t = __fdividef(1.0f, 1.0f + 0.3275911f * z);
    float poly = t * (0.254829592f + t * (-0.284496736f +
                 t * (1.421413741f + t * (-1.453152027f + t * 1.061405429f))));
    float erfv = 1.0f - poly * __expf(-z * z);
    erfv = (x < 0.f) ? -erfv : erfv;
    return 0.5f * x * (1.0f + erfv);
}

// ---------------------------------------------------------------------------
// Prep: transpose+convert weights to bf16 (n-major, k-contiguous) once/launch.
// WqkvT is the full 576x192 (Q rows 0..192, K rows 192..384, V rows 384..576).
__launch_bounds__(256)
__global__ void prep_weights_kernel(const float* __restrict__ w_qkv,
                                    const float* __restrict__ w_g1,
                                    const float* __restrict__ w_g2,
                                    ushort* __restrict__ WqkvT,
                                    ushort* __restrict__ W1T,
                                    ushort* __restrict__ W2T) {
    int idx = blockIdx.x * 256 + threadIdx.x;
    if (idx < 576 * 192) {
        int n = idx / 192, k = idx % 192;
        WqkvT[idx] = f2bf(w_qkv[(size_t)k * C3 + n]);
    }
    if (idx < 768 * 192) {
        int n = idx / 192, k = idx % 192;
        W1T[idx] = f2bf(w_g1[(size_t)k * C4 + n]);
    }
    if (idx < 192 * 768) {
        int n = idx / 768, k = idx % 768;
        W2T[idx] = f2bf(w_g2[(size_t)k * CDIM + n]);
    }
}

// ---------------------------------------------------------------------------
// K1: 1x1 conv == per-batch GEMM (fp32)
__launch_bounds__(256)
__global__ void conv1x1_kernel(const float* __restrict__ x,
                               const float* __restrict__ w1,
                               const float* __restrict__ b1,
                               float* __restrict__ f1) {
    __shared__ __align__(16) float As[16][68];
    __shared__ __align__(16) float Bs[16][64];
    const int tid = threadIdx.x;
    const int p0 = blockIdx.x * 64;
    const int m0 = blockIdx.y * 64;
    const int b  = blockIdx.z;
    const int tm = tid >> 4, tn = tid & 15;
    const int mload = tid >> 2, kload = (tid & 3) * 4;
    const int kw = tid >> 4, nw = (tid & 15) * 4;
    float acc[4][4] = {};
    const float* xb = x + (size_t)b * CDIM * HWSZ;
    for (int k0 = 0; k0 < CDIM; k0 += 16) {
        float4 av = *(const float4*)&w1[(size_t)(m0 + mload) * CDIM + k0 + kload];
        float4 bv = *(const float4*)&xb[(size_t)(k0 + kw) * HWSZ + p0 + nw];
        __syncthreads();
        As[kload + 0][mload] = av.x;
        As[kload + 1][mload] = av.y;
        As[kload + 2][mload] = av.z;
        As[kload + 3][mload] = av.w;
        *(float4*)&Bs[kw][nw] = bv;
        __syncthreads();
#pragma unroll
        for (int kk = 0; kk < 16; ++kk) {
            float a[4], bb[4];
            *(float4*)a  = *(const float4*)&As[kk][tm * 4];
            *(float4*)bb = *(const float4*)&Bs[kk][tn * 4];
#pragma unroll
            for (int i = 0; i < 4; ++i)
#pragma unroll
                for (int j = 0; j < 4; ++j) acc[i][j] += a[i] * bb[j];
        }
    }
    float* outb = f1 + (size_t)b * CDIM * HWSZ;
#pragma unroll
    for (int i = 0; i < 4; ++i) {
        int m = m0 + tm * 4 + i;
        float bias = b1[m];
        float4 o = make_float4(acc[i][0] + bias, acc[i][1] + bias,
                               acc[i][2] + bias, acc[i][3] + bias);
        *(float4*)&outb[(size_t)m * HWSZ + p0 + tn * 4] = o;
    }
}

// ---------------------------------------------------------------------------
// K2: depthwise 3x3 SAME, NCHW.
__launch_bounds__(256)
__global__ void dwconv_kernel(const float* __restrict__ f1,
                              const float* __restrict__ w_dw,
                              const float* __restrict__ b_dw,
                              float* __restrict__ f2) {
    unsigned int idx = blockIdx.x * 256u + threadIdx.x;
    int w = idx % WDIM;
    unsigned int r = idx / WDIM;
    int h = r % HDIM;
    unsigned int bc = r / HDIM;
    int c = bc % CDIM;
    const float* base = f1 + (size_t)bc * HWSZ;
    const float* wd = w_dw + c * 9;
    float acc = b_dw[c];
#pragma unroll
    for (int ky = 0; ky < 3; ++ky) {
        int hy = h + ky - 1;
        if (hy < 0 || hy >= HDIM) continue;
#pragma unroll
        for (int kx = 0; kx < 3; ++kx) {
            int wx = w + kx - 1;
            if (wx < 0 || wx >= WDIM) continue;
            acc += base[hy * WDIM + wx] * wd[ky * 3 + kx];
        }
    }
    f2[idx] = acc;
}

// ---------------------------------------------------------------------------
// K3: LayerNorm over C + window partition -> token-major pb[M][PBP] (bf16).
__launch_bounds__(256)
__global__ void ln_part_kernel(const float* __restrict__ f2,
                               const float* __restrict__ ln_g,
                               const float* __restrict__ ln_b,
                               ushort* __restrict__ pb) {
    __shared__ float T[CDIM][33];
    __shared__ float Rs[8][32], Rs2[8][32];
    __shared__ float Mu[32], Rsig[32];
    const int tid = threadIdx.x;
    const int wt = blockIdx.x, h = blockIdx.y, b = blockIdx.z;
    const int w0 = wt * 32;
    const size_t rowbase = (size_t)b * CDIM * HWSZ + (size_t)h * WDIM + w0;
    for (int idx = tid; idx < CDIM * 32; idx += 256) {
        int c = idx >> 5, j = idx & 31;
        T[c][j] = f2[rowbase + (size_t)c * HWSZ + j];
    }
    __syncthreads();
    {
        int j = tid & 31, q = tid >> 5;
        float s = 0.f, s2 = 0.f;
#pragma unroll
        for (int i = 0; i < 24; ++i) {
            float v = T[q * 24 + i][j];
            s += v; s2 += v * v;
        }
        Rs[q][j] = s; Rs2[q][j] = s2;
    }
    __syncthreads();
    if (tid < 32) {
        float s = 0.f, s2 = 0.f;
#pragma unroll
        for (int q = 0; q < 8; ++q) { s += Rs[q][tid]; s2 += Rs2[q][tid]; }
        float mu = s * (1.0f / CDIM);
        float var = s2 * (1.0f / CDIM) - mu * mu;
        Mu[tid] = mu;
        Rsig[tid] = rsqrtf(var + LN_EPS);
    }
    __syncthreads();
    const int l = tid & 63;
    const int jo = tid >> 6;
    for (int it = 0; it < 8; ++it) {
        int j = it * 4 + jo;
        int w = w0 + j;
        size_t token = ((size_t)(b * NWH + (h >> 3)) * NWH + (w >> 3)) * TOK
                       + ((h & 7) * 8 + (w & 7));
        float mu = Mu[j], rs = Rsig[j];
#pragma unroll
        for (int rep = 0; rep < 3; ++rep) {
            int c = l + rep * 64;
            pb[token * PBP + c] = f2bf((T[c][j] - mu) * rs * ln_g[c] + ln_b[c]);
        }
    }
}

// ---------------------------------------------------------------------------
// K4: MFMA attention. 1 window (64 tokens) per block, 4 waves.
// Per head: QKV GEMM (64x96, K=192, B-frags direct from global bf16 WqkvT),
// S = Q.K^T (MFMA, K=32), in-register softmax (16-lane shfl reduce),
// O = P.V^T (MFMA, K=64) -> oa fp32.
__launch_bounds__(256)
__global__ void attn_mfma_kernel(const ushort* __restrict__ pb,
                                 const ushort* __restrict__ WqkvT,
                                 const float* __restrict__ b_qkv,
                                 float* __restrict__ oa) {
    __shared__ __align__(16) ushort Pt[64 * PBP];    // 25600 B p tile, k-contig
    __shared__ __align__(16) ushort Qb[64 * 40];     //  5120 B Q (scale folded)
    __shared__ __align__(16) ushort Kb[64 * 40];     //  5120 B K
    __shared__ __align__(16) ushort Vt[32 * 72];     //  4608 B V^T (d rows, token-contig)
    __shared__ __align__(16) ushort Pbf[64 * 72];    //  9216 B softmax(P) bf16
    const int tid = threadIdx.x;
    const int lane = tid & 63, wave = tid >> 6;
    const int quad = lane >> 4, l16 = lane & 15;
    const int m0 = wave * 16;
    const size_t tok0 = (size_t)blockIdx.x * 64;

    // stage p tile: pure linear copy (pb pitch == Pt pitch == PBP)
    {
        const ushort* src = pb + tok0 * PBP;
        for (int i = tid * 8; i < 64 * PBP; i += 2048)
            *(uint4*)&Pt[i] = *(const uint4*)&src[i];
    }
    __syncthreads();

    for (int h = 0; h < HEADS; ++h) {
        // ---- QKV GEMM for this head: rows m0..m0+16 x 96 cols (Q|K|V) ----
        f32x4 acc[6];
#pragma unroll
        for (int t = 0; t < 6; ++t) acc[t] = (f32x4){0.f, 0.f, 0.f, 0.f};
#pragma unroll
        for (int kk = 0; kk < 6; ++kk) {
            bfrag a = *(const bfrag*)&Pt[(m0 + l16) * PBP + kk * 32 + quad * 8];
#pragma unroll
            for (int t = 0; t < 6; ++t) {
                const int nrow = (t < 2) ? (h * 32 + t * 16 + l16)
                               : (t < 4) ? (192 + h * 32 + (t - 2) * 16 + l16)
                                         : (384 + h * 32 + (t - 4) * 16 + l16);
                bfrag b = *(const bfrag*)&WqkvT[(size_t)nrow * 192 + kk * 32 + quad * 8];
                acc[t] = __builtin_amdgcn_mfma_f32_16x16x32_bf16(a, b, acc[t], 0, 0, 0);
            }
        }
        // write Q (scale folded), K, V^T to LDS
#pragma unroll
        for (int t = 0; t < 2; ++t) {
            float bq = b_qkv[h * 32 + t * 16 + l16];
            float bk = b_qkv[192 + h * 32 + t * 16 + l16];
            float bv = b_qkv[384 + h * 32 + t * 16 + l16];
#pragma unroll
            for (int reg = 0; reg < 4; ++reg) {
                int row = m0 + quad * 4 + reg;
                Qb[row * 40 + t * 16 + l16] = f2bf((acc[t][reg] + bq) * ATTN_SCALE);
                Kb[row * 40 + t * 16 + l16] = f2bf(acc[t + 2][reg] + bk);
                Vt[(t * 16 + l16) * 72 + row] = f2bf(acc[t + 4][reg] + bv);
            }
        }
        __syncthreads();

        // ---- S = Q.K^T (64x64, K=32): 4 col-tiles, 1 MFMA each ----
        f32x4 s[4];
        {
            bfrag aq = *(const bfrag*)&Qb[(m0 + l16) * 40 + quad * 8];
#pragma unroll
            for (int t = 0; t < 4; ++t) {
                bfrag b = *(const bfrag*)&Kb[(t * 16 + l16) * 40 + quad * 8];
                s[t] = __builtin_amdgcn_mfma_f32_16x16x32_bf16(
                    aq, b, (f32x4){0.f, 0.f, 0.f, 0.f}, 0, 0, 0);
            }
        }
        // ---- softmax per row (row = m0+quad*4+reg; 64 cols in 16 lanes x 4 tiles)
#pragma unroll
        for (int reg = 0; reg < 4; ++reg) {
            float mx = fmaxf(fmaxf(s[0][reg], s[1][reg]), fmaxf(s[2][reg], s[3][reg]));
            mx = fmaxf(mx, __shfl_xor(mx, 1));
            mx = fmaxf(mx, __shfl_xor(mx, 2));
            mx = fmaxf(mx, __shfl_xor(mx, 4));
            mx = fmaxf(mx, __shfl_xor(mx, 8));
            float e[4], sum = 0.f;
#pragma unroll
            for (int t = 0; t < 4; ++t) { e[t] = __expf(s[t][reg] - mx); sum += e[t]; }
            sum += __shfl_xor(sum, 1);
            sum += __shfl_xor(sum, 2);
            sum += __shfl_xor(sum, 4);
            sum += __shfl_xor(sum, 8);
            float inv = 1.0f / sum;
            int row = m0 + quad * 4 + reg;
#pragma unroll
            for (int t = 0; t < 4; ++t)
                Pbf[row * 72 + t * 16 + l16] = f2bf(e[t] * inv);
        }
        __syncthreads();

        // ---- O = P.V (64x32, K=64): 2 col-tiles x 2 k-steps ----
        f32x4 o[2];
        o[0] = (f32x4){0.f, 0.f, 0.f, 0.f};
        o[1] = (f32x4){0.f, 0.f, 0.f, 0.f};
#pragma unroll
        for (int kk = 0; kk < 2; ++kk) {
            bfrag a = *(const bfrag*)&Pbf[(m0 + l16) * 72 + kk * 32 + quad * 8];
#pragma unroll
            for (int t = 0; t < 2; ++t) {
                bfrag b = *(const bfrag*)&Vt[(t * 16 + l16) * 72 + kk * 32 + quad * 8];
                o[t] = __builtin_amdgcn_mfma_f32_16x16x32_bf16(a, b, o[t], 0, 0, 0);
            }
        }
#pragma unroll
        for (int t = 0; t < 2; ++t) {
            int col = h * 32 + t * 16 + l16;
#pragma unroll
            for (int reg = 0; reg < 4; ++reg) {
                int row = m0 + quad * 4 + reg;
                oa[(tok0 + row) * (size_t)CDIM + col] = o[t][reg];
            }
        }
        __syncthreads();   // protect Qb/Kb/Vt/Pbf before next head's writes
    }
}

// ---------------------------------------------------------------------------
// K5: MFMA GMLP, barrier-free main loop. Block = 64 tokens, 4 waves.
// All weight B-fragments read DIRECT from L2-resident global bf16 (no LDS
// staging, no barriers). Ab/Hb rows are wave-private (wave w owns rows
// 16w..16w+15): v = p@Wv+b; 12 hidden chunks: GEMM1 -> gelu -> GEMM2 acc.
// Epilogue: a_io *= (g + b_g2).
__launch_bounds__(256, 4)
__global__ void gmlp_mfma_kernel(const ushort* __restrict__ pb,
                                 const ushort* __restrict__ WvT,
                                 const float* __restrict__ b_qkv,
                                 const ushort* __restrict__ W1T,
                                 const float* __restrict__ b_g1,
                                 const ushort* __restrict__ W2T,
                                 const float* __restrict__ b_g2,
                                 float* __restrict__ a_io) {
    __shared__ __align__(16) ushort Ab[64 * PBP];  // 25600 B: p tile then V (bf16)
    __shared__ __align__(16) ushort Hb[64 * 72];   //  9216 B: gelu hidden chunk
    const int tid = threadIdx.x;
    const int lane = tid & 63, wave = tid >> 6;
    const int quad = lane >> 4, l16 = lane & 15;
    const int m0 = wave * 16;
    const size_t tok0 = (size_t)blockIdx.x * 64;

    // stage p tile: pure linear copy (pb pitch == Ab pitch == PBP)
    {
        const ushort* src = pb + tok0 * PBP;
        for (int i = tid * 8; i < 64 * PBP; i += 2048)
            *(uint4*)&Ab[i] = *(const uint4*)&src[i];
    }
    __syncthreads();   // the ONLY block-wide barrier

    // ---- v-GEMM: rows m0..m0+15 x 192, K=192; B-frags direct from WvT ----
    f32x4 vacc[12];
#pragma unroll
    for (int i = 0; i < 12; ++i) vacc[i] = (f32x4){0.f, 0.f, 0.f, 0.f};
#pragma unroll
    for (int nc = 0; nc < 3; ++nc) {
#pragma unroll
        for (int kk = 0; kk < 6; ++kk) {
            bfrag a = *(const bfrag*)&Ab[(m0 + l16) * PBP + kk * 32 + quad * 8];
#pragma unroll
            for (int t = 0; t < 4; ++t) {
                bfrag b = *(const bfrag*)&WvT[(size_t)(nc * 64 + t * 16 + l16) * 192
                                              + kk * 32 + quad * 8];
                vacc[nc * 4 + t] = __builtin_amdgcn_mfma_f32_16x16x32_bf16(
                    a, b, vacc[nc * 4 + t], 0, 0, 0);
            }
        }
    }
    // write V (bf16) into this wave's own rows of Ab (wave-private)
#pragma unroll
    for (int i = 0; i < 12; ++i) {
        int n = i * 16 + l16;
        float bias = b_qkv[384 + n];
#pragma unroll
        for (int reg = 0; reg < 4; ++reg) {
            int r = m0 + quad * 4 + reg;
            Ab[r * PBP + n] = f2bf(vacc[i][reg] + bias);
        }
    }
    // in-wave LDS RAW fence (V writes -> GEMM1 reads); wave-local, no barrier
    asm volatile("s_waitcnt lgkmcnt(0)" ::: "memory");

    // ---- hidden loop (barrier-free; Hb rows wave-private) ----
    f32x4 acc2[12];
#pragma unroll
    for (int i = 0; i < 12; ++i) acc2[i] = (f32x4){0.f, 0.f, 0.f, 0.f};
    for (int hc = 0; hc < 12; ++hc) {
        // GEMM1: H chunk rows m0..m0+15 x 64, K=192; B-frags direct from W1T
        f32x4 acc1[4];
#pragma unroll
        for (int t = 0; t < 4; ++t) acc1[t] = (f32x4){0.f, 0.f, 0.f, 0.f};
#pragma unroll
        for (int kk = 0; kk < 6; ++kk) {
            bfrag a = *(const bfrag*)&Ab[(m0 + l16) * PBP + kk * 32 + quad * 8];
#pragma unroll
            for (int t = 0; t < 4; ++t) {
                bfrag b = *(const bfrag*)&W1T[((size_t)hc * 64 + t * 16 + l16) * 192
                                              + kk * 32 + quad * 8];
                acc1[t] = __builtin_amdgcn_mfma_f32_16x16x32_bf16(a, b, acc1[t], 0, 0, 0);
            }
        }
        // gelu -> Hb (own-wave rows)
#pragma unroll
        for (int t = 0; t < 4; ++t) {
            int n = t * 16 + l16;
            float bb = b_g1[hc * 64 + n];
#pragma unroll
            for (int reg = 0; reg < 4; ++reg) {
                float xv = acc1[t][reg] + bb;
                Hb[(m0 + quad * 4 + reg) * 72 + n] = f2bf(gelu_erf(xv));
            }
        }
        // in-wave LDS RAW fence (H writes -> GEMM2 reads)
        asm volatile("s_waitcnt lgkmcnt(0)" ::: "memory");
        // GEMM2 accumulate: 64x192, K=64; B-frags direct from W2T [192][768]
#pragma unroll
        for (int kk = 0; kk < 2; ++kk) {
            bfrag a = *(const bfrag*)&Hb[(m0 + l16) * 72 + kk * 32 + quad * 8];
#pragma unroll
            for (int t = 0; t < 12; ++t) {
                bfrag b = *(const bfrag*)&W2T[(size_t)(t * 16 + l16) * 768
                                              + hc * 64 + kk * 32 + quad * 8];
                acc2[t] = __builtin_amdgcn_mfma_f32_16x16x32_bf16(a, b, acc2[t], 0, 0, 0);
            }
        }
        // WAR fence: next hc overwrites Hb rows this wave just read
        asm volatile("s_waitcnt lgkmcnt(0)" ::: "memory");
    }
    // epilogue: product with attention output, in place
#pragma unroll
    for (int t = 0; t < 12; ++t) {
        int c = t * 16 + l16;
        float bg = b_g2[c];
#pragma unroll
        for (int reg = 0; reg < 4; ++reg) {
            size_t idx = (tok0 + m0 + quad * 4 + reg) * CDIM + c;
            a_io[idx] *= (acc2[t][reg] + bg);
        }
    }
}

// ---------------------------------------------------------------------------
// K7: fused = product @ w_proj + b (in-place), recon loss vs pb (bf16 target).
__launch_bounds__(256)
__global__ void proj_recon_kernel(const float* __restrict__ w_proj,
                                  const float* __restrict__ b_proj,
                                  const float* __restrict__ w_rec,
                                  const float* __restrict__ b_rec,
                                  const ushort* __restrict__ pb,
                                  float* __restrict__ a_io,
                                  float* __restrict__ loss) {
    __shared__ float T[64 * 196];
    __shared__ float WT[16 * 196];
    __shared__ float red[256];
    const int tid = threadIdx.x;
    const size_t m0 = (size_t)blockIdx.x * 64;
    const int tr = tid >> 5, tc = tid & 31;
    for (int i4 = tid * 4; i4 < 64 * 192; i4 += 1024) {
        float4 v = *(const float4*)&a_io[m0 * CDIM + i4];
        int r = i4 / 192, c = i4 - r * 192;
        *(float4*)&T[r * 196 + c] = v;
    }
    float facc[8][6] = {};
    for (int k0 = 0; k0 < 192; k0 += 16) {
        __syncthreads();
        for (int i4 = tid * 4; i4 < 16 * 192; i4 += 1024) {
            int kk = i4 / 192, c = i4 - kk * 192;
            float4 w = *(const float4*)&w_proj[(size_t)(k0 + kk) * CDIM + c];
            *(float4*)&WT[kk * 196 + c] = w;
        }
        __syncthreads();
#pragma unroll
        for (int k4 = 0; k4 < 16; k4 += 4) {
            float4 a[8];
#pragma unroll
            for (int i = 0; i < 8; ++i)
                a[i] = *(const float4*)&T[(tr + 8 * i) * 196 + k0 + k4];
#pragma unroll
            for (int kk = 0; kk < 4; ++kk) {
                float b[6];
#pragma unroll
                for (int j = 0; j < 6; ++j) b[j] = WT[(k4 + kk) * 196 + tc + 32 * j];
#pragma unroll
                for (int i = 0; i < 8; ++i) {
                    float av = (kk == 0) ? a[i].x : (kk == 1) ? a[i].y
                             : (kk == 2) ? a[i].z : a[i].w;
#pragma unroll
                    for (int j = 0; j < 6; ++j) facc[i][j] += av * b[j];
                }
            }
        }
    }
    __syncthreads();
#pragma unroll
    for (int j = 0; j < 6; ++j) {
        float bp = b_proj[tc + 32 * j];
#pragma unroll
        for (int i = 0; i < 8; ++i) {
            float fv = facc[i][j] + bp;
            T[(tr + 8 * i) * 196 + tc + 32 * j] = fv;
            a_io[(m0 + tr + 8 * i) * CDIM + tc + 32 * j] = fv;
        }
    }
    float racc[8][6] = {};
    for (int k0 = 0; k0 < 192; k0 += 16) {
        __syncthreads();
        for (int i4 = tid * 4; i4 < 16 * 192; i4 += 1024) {
            int kk = i4 / 192, c = i4 - kk * 192;
            float4 w = *(const float4*)&w_rec[(size_t)(k0 + kk) * CDIM + c];
            *(float4*)&WT[kk * 196 + c] = w;
        }
        __syncthreads();
#pragma unroll
        for (int k4 = 0; k4 < 16; k4 += 4) {
            float4 a[8];
#pragma unroll
            for (int i = 0; i < 8; ++i)
                a[i] = *(const float4*)&T[(tr + 8 * i) * 196 + k0 + k4];
#pragma unroll
            for (int kk = 0; kk < 4; ++kk) {
                float b[6];
#pragma unroll
                for (int j = 0; j < 6; ++j) b[j] = WT[(k4 + kk) * 196 + tc + 32 * j];
#pragma unroll
                for (int i = 0; i < 8; ++i) {
                    float av = (kk == 0) ? a[i].x : (kk == 1) ? a[i].y
                             : (kk == 2) ? a[i].z : a[i].w;
#pragma unroll
                    for (int j = 0; j < 6; ++j) racc[i][j] += av * b[j];
                }
            }
        }
    }
    float ls = 0.f;
#pragma unroll
    for (int j = 0; j < 6; ++j) {
        float br = b_rec[tc + 32 * j];
#pragma unroll
        for (int i = 0; i < 8; ++i) {
            float rv = racc[i][j] + br;
            ls += fabsf(rv - bf2f(pb[(m0 + tr + 8 * i) * PBP + tc + 32 * j]));
        }
    }
    red[tid] = ls;
    __syncthreads();
    for (int s = 128; s > 0; s >>= 1) {
        if (tid < s) red[tid] += red[tid + s];
        __syncthreads();
    }
    if (tid == 0) atomicAdd(loss, red[0] * (0.1f / (float)IMGSZ));
}

// ---------------------------------------------------------------------------
// K8: window reverse + residual.
__launch_bounds__(256)
__global__ void reverse_res_kernel(const float* __restrict__ fused,
                                   const float* __restrict__ x,
                                   float* __restrict__ out) {
    __shared__ float T[CDIM][33];
    const int tid = threadIdx.x;
    const int wt = blockIdx.x, h = blockIdx.y, b = blockIdx.z;
    const int w0 = wt * 32;
    const int l = tid & 63, jo = tid >> 6;
    for (int it = 0; it < 8; ++it) {
        int j = it * 4 + jo;
        int w = w0 + j;
        size_t token = ((size_t)(b * NWH + (h >> 3)) * NWH + (w >> 3)) * TOK
                       + ((h & 7) * 8 + (w & 7));
#pragma unroll
        for (int rep = 0; rep < 3; ++rep) {
            int c = l + rep * 64;
            T[c][j] = fused[token * CDIM + c];
        }
    }
    __syncthreads();
    const size_t rowbase = (size_t)b * CDIM * HWSZ + (size_t)h * WDIM + w0;
    for (int idx = tid; idx < CDIM * 32; idx += 256) {
        int c = idx >> 5, j = idx & 31;
        size_t gp = rowbase + (size_t)c * HWSZ + j;
        out[gp] = T[c][j] + x[gp];
    }
}

// ---------------------------------------------------------------------------
extern "C" void kernel_launch(void* const* d_in, const int* in_sizes, int n_in,
                              void* d_out, int out_size, void* d_ws, size_t ws_size,
                              hipStream_t stream) {
    const float* x      = (const float*)d_in[0];
    const float* w_pre1 = (const float*)d_in[1];
    const float* b_pre1 = (const float*)d_in[2];
    const float* w_dw   = (const float*)d_in[3];
    const float* b_dw   = (const float*)d_in[4];
    const float* ln_g   = (const float*)d_in[5];
    const float* ln_b   = (const float*)d_in[6];
    const float* w_qkv  = (const float*)d_in[7];
    const float* b_qkv  = (const float*)d_in[8];
    const float* w_proj = (const float*)d_in[9];
    const float* b_proj = (const float*)d_in[10];
    const float* w_g1   = (const float*)d_in[11];
    const float* b_g1   = (const float*)d_in[12];
    const float* w_g2   = (const float*)d_in[13];
    const float* b_g2   = (const float*)d_in[14];
    const float* w_rec  = (const float*)d_in[15];
    const float* b_rec  = (const float*)d_in[16];

    float* OutR = (float*)d_out;
    float* loss = OutR + (size_t)IMGSZ;
    float* A    = (float*)d_ws;            // 154 MB fp32 region

    // d_out layout during pipeline (front->back):
    //  [f1 fp32 full]  ->  [pb bf16 (pitch 200) ~80MB | bf16 weights ~0.8MB]
    //  final: out fp32 full + loss scalar
    ushort* pb    = (ushort*)d_out;                    // MTOK*PBP bf16
    ushort* WqkvT = pb    + (size_t)MTOK * PBP;        // 576x192 (n-major, k-contig)
    ushort* W1T   = WqkvT + 576 * 192;                 // 768x192
    ushort* W2T   = W1T   + 768 * 192;                 // 192x768
    ushort* WvT   = WqkvT + 384 * 192;                 // V rows of WqkvT (for gmlp)

    hipMemsetAsync(loss, 0, sizeof(float), stream);

    // K1: f1 = conv1x1(x) -> d_out (fp32)
    conv1x1_kernel<<<dim3(HWSZ / 64, CDIM / 64, BATCH), 256, 0, stream>>>(
        x, w_pre1, b_pre1, OutR);
    // K2: f2 = dwconv(f1) -> A
    dwconv_kernel<<<IMGSZ / 256, 256, 0, stream>>>(OutR, w_dw, b_dw, A);
    // prep bf16 weights (after f1 is dead)
    prep_weights_kernel<<<(768 * 192 + 255) / 256, 256, 0, stream>>>(
        w_qkv, w_g1, w_g2, WqkvT, W1T, W2T);
    // K3: pb = LN+partition(f2) -> d_out front (bf16, pitch PBP)
    ln_part_kernel<<<dim3(WDIM / 32, HDIM, BATCH), 256, 0, stream>>>(
        A, ln_g, ln_b, pb);
    // K4: MFMA attention -> A
    attn_mfma_kernel<<<NWIN, 256, 0, stream>>>(pb, WqkvT, b_qkv, A);
    // K5: A = attn .* gmlp(v) in place (MFMA, barrier-free)
    gmlp_mfma_kernel<<<MTOK / 64, 256, 0, stream>>>(
        pb, WvT, b_qkv, W1T, b_g1, W2T, b_g2, A);
    // K7: A = product @ w_proj + b (in place); recon loss vs pb
    proj_recon_kernel<<<MTOK / 64, 256, 0, stream>>>(
        w_proj, b_proj, w_rec, b_rec, pb, A, loss);
    // K8: out = reverse(A) + x -> d_out
    reverse_res_kernel<<<dim3(WDIM / 32, HDIM, BATCH), 256, 0, stream>>>(
        A, x, OutR);
}

// Round 5
// 2431.912 us; speedup vs baseline: 1.1474x; 1.1474x over previous
//
#include <hip/hip_runtime.h>
#include <hip/hip_bf16.h>
#include <math.h>

// Problem constants
#define BATCH 4
#define CDIM 192
#define HDIM 224
#define WDIM 224
#define HWSZ (HDIM * WDIM)            // 50176
#define NWH 28                        // 224/8
#define NWIN (BATCH * NWH * NWH)      // 3136
#define TOK 64
#define MTOK (NWIN * TOK)             // 200704
#define HEADS 6
#define C3 (3 * CDIM)                 // 576
#define C4 (4 * CDIM)                 // 768
#define IMGSZ (BATCH * CDIM * HWSZ)   // 38535168
#define ATTN_SCALE 0.17677669529663687f
#define LN_EPS 1e-6f
#define PBP 200                        // pb row pitch (ushorts), 400 B, 16B-aligned

typedef __attribute__((ext_vector_type(8))) short bfrag;   // 8 bf16 (4 VGPRs)
typedef __attribute__((ext_vector_type(4))) float f32x4;

__device__ __forceinline__ float bf2f(unsigned short u) {
    union { unsigned int i; float f; } v; v.i = ((unsigned int)u) << 16; return v.f;
}
__device__ __forceinline__ unsigned short f2bf(float f) {
    union { unsigned int i; float f; } v; v.f = f;
    unsigned int r = (v.i + 0x7FFFu + ((v.i >> 16) & 1u)) >> 16;   // RNE
    return (unsigned short)r;
}
// exact-erf GELU via Abramowitz-Stegun 7.1.26 (|erf err| <= 1.5e-7)
__device__ __forceinline__ float gelu_erf(float x) {
    float z = fabsf(x) * 0.70710678118654752f;
    float t = __fdividef(1.0f, 1.0f + 0.3275911f * z);
    float poly = t * (0.254829592f + t * (-0.284496736f +
                 t * (1.421413741f + t * (-1.453152027f + t * 1.061405429f))));
    float erfv = 1.0f - poly * __expf(-z * z);
    erfv = (x < 0.f) ? -erfv : erfv;
    return 0.5f * x * (1.0f + erfv);
}

// ---------------------------------------------------------------------------
// Prep: transpose+convert weights to bf16 (n-major, k-contiguous) once/launch.
// WqkvT is the full 576x192 (Q rows 0..192, K rows 192..384, V rows 384..576).
__launch_bounds__(256)
__global__ void prep_weights_kernel(const float* __restrict__ w_qkv,
                                    const float* __restrict__ w_g1,
                                    const float* __restrict__ w_g2,
                                    ushort* __restrict__ WqkvT,
                                    ushort* __restrict__ W1T,
                                    ushort* __restrict__ W2T) {
    int idx = blockIdx.x * 256 + threadIdx.x;
    if (idx < 576 * 192) {
        int n = idx / 192, k = idx % 192;
        WqkvT[idx] = f2bf(w_qkv[(size_t)k * C3 + n]);
    }
    if (idx < 768 * 192) {
        int n = idx / 192, k = idx % 192;
        W1T[idx] = f2bf(w_g1[(size_t)k * C4 + n]);
    }
    if (idx < 192 * 768) {
        int n = idx / 768, k = idx % 768;
        W2T[idx] = f2bf(w_g2[(size_t)k * CDIM + n]);
    }
}

// ---------------------------------------------------------------------------
// K1: 1x1 conv == per-batch GEMM (fp32)
__launch_bounds__(256)
__global__ void conv1x1_kernel(const float* __restrict__ x,
                               const float* __restrict__ w1,
                               const float* __restrict__ b1,
                               float* __restrict__ f1) {
    __shared__ __align__(16) float As[16][68];
    __shared__ __align__(16) float Bs[16][64];
    const int tid = threadIdx.x;
    const int p0 = blockIdx.x * 64;
    const int m0 = blockIdx.y * 64;
    const int b  = blockIdx.z;
    const int tm = tid >> 4, tn = tid & 15;
    const int mload = tid >> 2, kload = (tid & 3) * 4;
    const int kw = tid >> 4, nw = (tid & 15) * 4;
    float acc[4][4] = {};
    const float* xb = x + (size_t)b * CDIM * HWSZ;
    for (int k0 = 0; k0 < CDIM; k0 += 16) {
        float4 av = *(const float4*)&w1[(size_t)(m0 + mload) * CDIM + k0 + kload];
        float4 bv = *(const float4*)&xb[(size_t)(k0 + kw) * HWSZ + p0 + nw];
        __syncthreads();
        As[kload + 0][mload] = av.x;
        As[kload + 1][mload] = av.y;
        As[kload + 2][mload] = av.z;
        As[kload + 3][mload] = av.w;
        *(float4*)&Bs[kw][nw] = bv;
        __syncthreads();
#pragma unroll
        for (int kk = 0; kk < 16; ++kk) {
            float a[4], bb[4];
            *(float4*)a  = *(const float4*)&As[kk][tm * 4];
            *(float4*)bb = *(const float4*)&Bs[kk][tn * 4];
#pragma unroll
            for (int i = 0; i < 4; ++i)
#pragma unroll
                for (int j = 0; j < 4; ++j) acc[i][j] += a[i] * bb[j];
        }
    }
    float* outb = f1 + (size_t)b * CDIM * HWSZ;
#pragma unroll
    for (int i = 0; i < 4; ++i) {
        int m = m0 + tm * 4 + i;
        float bias = b1[m];
        float4 o = make_float4(acc[i][0] + bias, acc[i][1] + bias,
                               acc[i][2] + bias, acc[i][3] + bias);
        *(float4*)&outb[(size_t)m * HWSZ + p0 + tn * 4] = o;
    }
}

// ---------------------------------------------------------------------------
// K2: depthwise 3x3 SAME, NCHW.
__launch_bounds__(256)
__global__ void dwconv_kernel(const float* __restrict__ f1,
                              const float* __restrict__ w_dw,
                              const float* __restrict__ b_dw,
                              float* __restrict__ f2) {
    unsigned int idx = blockIdx.x * 256u + threadIdx.x;
    int w = idx % WDIM;
    unsigned int r = idx / WDIM;
    int h = r % HDIM;
    unsigned int bc = r / HDIM;
    int c = bc % CDIM;
    const float* base = f1 + (size_t)bc * HWSZ;
    const float* wd = w_dw + c * 9;
    float acc = b_dw[c];
#pragma unroll
    for (int ky = 0; ky < 3; ++ky) {
        int hy = h + ky - 1;
        if (hy < 0 || hy >= HDIM) continue;
#pragma unroll
        for (int kx = 0; kx < 3; ++kx) {
            int wx = w + kx - 1;
            if (wx < 0 || wx >= WDIM) continue;
            acc += base[hy * WDIM + wx] * wd[ky * 3 + kx];
        }
    }
    f2[idx] = acc;
}

// ---------------------------------------------------------------------------
// K3: LayerNorm over C + window partition -> token-major pb[M][PBP] (bf16).
__launch_bounds__(256)
__global__ void ln_part_kernel(const float* __restrict__ f2,
                               const float* __restrict__ ln_g,
                               const float* __restrict__ ln_b,
                               ushort* __restrict__ pb) {
    __shared__ float T[CDIM][33];
    __shared__ float Rs[8][32], Rs2[8][32];
    __shared__ float Mu[32], Rsig[32];
    const int tid = threadIdx.x;
    const int wt = blockIdx.x, h = blockIdx.y, b = blockIdx.z;
    const int w0 = wt * 32;
    const size_t rowbase = (size_t)b * CDIM * HWSZ + (size_t)h * WDIM + w0;
    for (int idx = tid; idx < CDIM * 32; idx += 256) {
        int c = idx >> 5, j = idx & 31;
        T[c][j] = f2[rowbase + (size_t)c * HWSZ + j];
    }
    __syncthreads();
    {
        int j = tid & 31, q = tid >> 5;
        float s = 0.f, s2 = 0.f;
#pragma unroll
        for (int i = 0; i < 24; ++i) {
            float v = T[q * 24 + i][j];
            s += v; s2 += v * v;
        }
        Rs[q][j] = s; Rs2[q][j] = s2;
    }
    __syncthreads();
    if (tid < 32) {
        float s = 0.f, s2 = 0.f;
#pragma unroll
        for (int q = 0; q < 8; ++q) { s += Rs[q][tid]; s2 += Rs2[q][tid]; }
        float mu = s * (1.0f / CDIM);
        float var = s2 * (1.0f / CDIM) - mu * mu;
        Mu[tid] = mu;
        Rsig[tid] = rsqrtf(var + LN_EPS);
    }
    __syncthreads();
    const int l = tid & 63;
    const int jo = tid >> 6;
    for (int it = 0; it < 8; ++it) {
        int j = it * 4 + jo;
        int w = w0 + j;
        size_t token = ((size_t)(b * NWH + (h >> 3)) * NWH + (w >> 3)) * TOK
                       + ((h & 7) * 8 + (w & 7));
        float mu = Mu[j], rs = Rsig[j];
#pragma unroll
        for (int rep = 0; rep < 3; ++rep) {
            int c = l + rep * 64;
            pb[token * PBP + c] = f2bf((T[c][j] - mu) * rs * ln_g[c] + ln_b[c]);
        }
    }
}

// ---------------------------------------------------------------------------
// K4: MFMA attention. 1 window (64 tokens) per block, 4 waves.
// Per head: QKV GEMM (64x96, K=192, B-frags direct from global bf16 WqkvT),
// S = Q.K^T (MFMA, K=32), in-register softmax (16-lane shfl reduce),
// O = P.V^T (MFMA, K=64) -> oa fp32.
__launch_bounds__(256)
__global__ void attn_mfma_kernel(const ushort* __restrict__ pb,
                                 const ushort* __restrict__ WqkvT,
                                 const float* __restrict__ b_qkv,
                                 float* __restrict__ oa) {
    __shared__ __align__(16) ushort Pt[64 * PBP];    // 25600 B p tile, k-contig
    __shared__ __align__(16) ushort Qb[64 * 40];     //  5120 B Q (scale folded)
    __shared__ __align__(16) ushort Kb[64 * 40];     //  5120 B K
    __shared__ __align__(16) ushort Vt[32 * 72];     //  4608 B V^T (d rows, token-contig)
    __shared__ __align__(16) ushort Pbf[64 * 72];    //  9216 B softmax(P) bf16
    const int tid = threadIdx.x;
    const int lane = tid & 63, wave = tid >> 6;
    const int quad = lane >> 4, l16 = lane & 15;
    const int m0 = wave * 16;
    const size_t tok0 = (size_t)blockIdx.x * 64;

    // stage p tile: pure linear copy (pb pitch == Pt pitch == PBP)
    {
        const ushort* src = pb + tok0 * PBP;
        for (int i = tid * 8; i < 64 * PBP; i += 2048)
            *(uint4*)&Pt[i] = *(const uint4*)&src[i];
    }
    __syncthreads();

    for (int h = 0; h < HEADS; ++h) {
        // ---- QKV GEMM for this head: rows m0..m0+16 x 96 cols (Q|K|V) ----
        f32x4 acc[6];
#pragma unroll
        for (int t = 0; t < 6; ++t) acc[t] = (f32x4){0.f, 0.f, 0.f, 0.f};
#pragma unroll
        for (int kk = 0; kk < 6; ++kk) {
            bfrag a = *(const bfrag*)&Pt[(m0 + l16) * PBP + kk * 32 + quad * 8];
#pragma unroll
            for (int t = 0; t < 6; ++t) {
                const int nrow = (t < 2) ? (h * 32 + t * 16 + l16)
                               : (t < 4) ? (192 + h * 32 + (t - 2) * 16 + l16)
                                         : (384 + h * 32 + (t - 4) * 16 + l16);
                bfrag b = *(const bfrag*)&WqkvT[(size_t)nrow * 192 + kk * 32 + quad * 8];
                acc[t] = __builtin_amdgcn_mfma_f32_16x16x32_bf16(a, b, acc[t], 0, 0, 0);
            }
        }
        // write Q (scale folded), K, V^T to LDS
#pragma unroll
        for (int t = 0; t < 2; ++t) {
            float bq = b_qkv[h * 32 + t * 16 + l16];
            float bk = b_qkv[192 + h * 32 + t * 16 + l16];
            float bv = b_qkv[384 + h * 32 + t * 16 + l16];
#pragma unroll
            for (int reg = 0; reg < 4; ++reg) {
                int row = m0 + quad * 4 + reg;
                Qb[row * 40 + t * 16 + l16] = f2bf((acc[t][reg] + bq) * ATTN_SCALE);
                Kb[row * 40 + t * 16 + l16] = f2bf(acc[t + 2][reg] + bk);
                Vt[(t * 16 + l16) * 72 + row] = f2bf(acc[t + 4][reg] + bv);
            }
        }
        __syncthreads();

        // ---- S = Q.K^T (64x64, K=32): 4 col-tiles, 1 MFMA each ----
        f32x4 s[4];
        {
            bfrag aq = *(const bfrag*)&Qb[(m0 + l16) * 40 + quad * 8];
#pragma unroll
            for (int t = 0; t < 4; ++t) {
                bfrag b = *(const bfrag*)&Kb[(t * 16 + l16) * 40 + quad * 8];
                s[t] = __builtin_amdgcn_mfma_f32_16x16x32_bf16(
                    aq, b, (f32x4){0.f, 0.f, 0.f, 0.f}, 0, 0, 0);
            }
        }
        // ---- softmax per row (row = m0+quad*4+reg; 64 cols in 16 lanes x 4 tiles)
#pragma unroll
        for (int reg = 0; reg < 4; ++reg) {
            float mx = fmaxf(fmaxf(s[0][reg], s[1][reg]), fmaxf(s[2][reg], s[3][reg]));
            mx = fmaxf(mx, __shfl_xor(mx, 1));
            mx = fmaxf(mx, __shfl_xor(mx, 2));
            mx = fmaxf(mx, __shfl_xor(mx, 4));
            mx = fmaxf(mx, __shfl_xor(mx, 8));
            float e[4], sum = 0.f;
#pragma unroll
            for (int t = 0; t < 4; ++t) { e[t] = __expf(s[t][reg] - mx); sum += e[t]; }
            sum += __shfl_xor(sum, 1);
            sum += __shfl_xor(sum, 2);
            sum += __shfl_xor(sum, 4);
            sum += __shfl_xor(sum, 8);
            float inv = 1.0f / sum;
            int row = m0 + quad * 4 + reg;
#pragma unroll
            for (int t = 0; t < 4; ++t)
                Pbf[row * 72 + t * 16 + l16] = f2bf(e[t] * inv);
        }
        __syncthreads();

        // ---- O = P.V (64x32, K=64): 2 col-tiles x 2 k-steps ----
        f32x4 o[2];
        o[0] = (f32x4){0.f, 0.f, 0.f, 0.f};
        o[1] = (f32x4){0.f, 0.f, 0.f, 0.f};
#pragma unroll
        for (int kk = 0; kk < 2; ++kk) {
            bfrag a = *(const bfrag*)&Pbf[(m0 + l16) * 72 + kk * 32 + quad * 8];
#pragma unroll
            for (int t = 0; t < 2; ++t) {
                bfrag b = *(const bfrag*)&Vt[(t * 16 + l16) * 72 + kk * 32 + quad * 8];
                o[t] = __builtin_amdgcn_mfma_f32_16x16x32_bf16(a, b, o[t], 0, 0, 0);
            }
        }
#pragma unroll
        for (int t = 0; t < 2; ++t) {
            int col = h * 32 + t * 16 + l16;
#pragma unroll
            for (int reg = 0; reg < 4; ++reg) {
                int row = m0 + quad * 4 + reg;
                oa[(tok0 + row) * (size_t)CDIM + col] = o[t][reg];
            }
        }
        __syncthreads();   // protect Qb/Kb/Vt/Pbf before next head's writes
    }
}

// ---------------------------------------------------------------------------
// K5: MFMA GMLP with T14 async-staged LDS weights. Block = 64 tokens, 4 waves.
// Weight chunks staged in LDS (round-2 layouts), but the global loads of the
// NEXT chunk are issued in registers BEFORE computing the current chunk, so
// L2 latency hides under MFMA+gelu; between barriers only the ds_write runs.
// v = p@Wv+b; 12 hidden chunks: GEMM1 -> gelu -> GEMM2 acc.
// Epilogue: a_io *= (g + b_g2).
__launch_bounds__(256, 2)
__global__ void gmlp_mfma_kernel(const ushort* __restrict__ pb,
                                 const ushort* __restrict__ WvT,
                                 const float* __restrict__ b_qkv,
                                 const ushort* __restrict__ W1T,
                                 const float* __restrict__ b_g1,
                                 const ushort* __restrict__ W2T,
                                 const float* __restrict__ b_g2,
                                 float* __restrict__ a_io) {
    __shared__ __align__(16) ushort Ab[64 * PBP];   // 25600 B: p tile then V (bf16)
    __shared__ __align__(16) ushort Wb[192 * 72];   // 27648 B: weight chunk (2 layouts)
    __shared__ __align__(16) ushort Hb[64 * 72];    //  9216 B: gelu hidden chunk
    const int tid = threadIdx.x;
    const int lane = tid & 63, wave = tid >> 6;
    const int quad = lane >> 4, l16 = lane & 15;
    const int m0 = wave * 16;
    const size_t tok0 = (size_t)blockIdx.x * 64;

    uint4 st[6];   // in-flight next weight chunk (24 KiB / 256 thr = 96 B/thr)

    // 64x192 chunk, rows k-contiguous (W1-like): load / write pitch-200
#define LOAD_CHUNK_A(SRC)                                                     \
    _Pragma("unroll")                                                         \
    for (int p = 0; p < 6; ++p)                                               \
        st[p] = *(const uint4*)&(SRC)[tid * 8 + p * 2048];
#define WRITE_CHUNK_A()                                                       \
    _Pragma("unroll")                                                         \
    for (int p = 0; p < 6; ++p) {                                             \
        int idx = tid * 8 + p * 2048;                                         \
        *(uint4*)&Wb[(idx / 192) * 200 + idx % 192] = st[p];                  \
    }
    // 192x64 chunk of W2T[192][768] (k-contiguous cols hc*64..): pitch-72
#define LOAD_CHUNK_B(HC)                                                      \
    _Pragma("unroll")                                                         \
    for (int p = 0; p < 6; ++p) {                                             \
        int idx = tid * 8 + p * 2048;                                         \
        st[p] = *(const uint4*)&W2T[(size_t)(idx >> 6) * 768 + (HC) * 64      \
                                    + (idx & 63)];                            \
    }
#define WRITE_CHUNK_B()                                                       \
    _Pragma("unroll")                                                         \
    for (int p = 0; p < 6; ++p) {                                             \
        int idx = tid * 8 + p * 2048;                                         \
        *(uint4*)&Wb[(idx >> 6) * 72 + (idx & 63)] = st[p];                   \
    }

    // stage p tile: pure linear copy (pb pitch == Ab pitch == PBP)
    {
        const ushort* src = pb + tok0 * PBP;
        for (int i = tid * 8; i < 64 * PBP; i += 2048)
            *(uint4*)&Ab[i] = *(const uint4*)&src[i];
    }
    LOAD_CHUNK_A(WvT);                    // st = Wv(0)
    __syncthreads();                      // Ab staged (Wb not yet read)
    WRITE_CHUNK_A();                      // Wb = Wv(0)
    LOAD_CHUNK_A(WvT + 12288);            // st = Wv(1), flies under computeV(0)
    __syncthreads();

    // ---- v-GEMM: rows m0..m0+15 x 192, K=192, 3 chunks of 64 N-cols ----
    f32x4 vacc[12];
#pragma unroll
    for (int i = 0; i < 12; ++i) vacc[i] = (f32x4){0.f, 0.f, 0.f, 0.f};

#define COMPUTE_V(NC)                                                         \
    _Pragma("unroll")                                                         \
    for (int kk = 0; kk < 6; ++kk) {                                          \
        bfrag a = *(const bfrag*)&Ab[(m0 + l16) * PBP + kk * 32 + quad * 8];  \
        _Pragma("unroll")                                                     \
        for (int t = 0; t < 4; ++t) {                                         \
            bfrag b = *(const bfrag*)&Wb[(t * 16 + l16) * 200 + kk * 32       \
                                         + quad * 8];                         \
            vacc[(NC) * 4 + t] = __builtin_amdgcn_mfma_f32_16x16x32_bf16(     \
                a, b, vacc[(NC) * 4 + t], 0, 0, 0);                           \
        }                                                                     \
    }

    COMPUTE_V(0);
    __syncthreads();
    WRITE_CHUNK_A();                      // Wb = Wv(1)
    LOAD_CHUNK_A(WvT + 2 * 12288);        // st = Wv(2)
    __syncthreads();
    COMPUTE_V(1);
    __syncthreads();
    WRITE_CHUNK_A();                      // Wb = Wv(2)
    LOAD_CHUNK_A(W1T);                    // st = W1(0)
    __syncthreads();
    COMPUTE_V(2);
    // write V (bf16) into this wave's own rows of Ab (wave-private rows;
    // two barriers before GEMM1 reads guarantee LDS drain)
#pragma unroll
    for (int i = 0; i < 12; ++i) {
        int n = i * 16 + l16;
        float bias = b_qkv[384 + n];
#pragma unroll
        for (int reg = 0; reg < 4; ++reg) {
            int r = m0 + quad * 4 + reg;
            Ab[r * PBP + n] = f2bf(vacc[i][reg] + bias);
        }
    }
    __syncthreads();
    WRITE_CHUNK_A();                      // Wb = W1(0)
    LOAD_CHUNK_B(0);                      // st = W2(0)
    __syncthreads();

    // ---- hidden loop: 12 chunks of 64 hidden cols ----
    f32x4 acc2[12];
#pragma unroll
    for (int i = 0; i < 12; ++i) acc2[i] = (f32x4){0.f, 0.f, 0.f, 0.f};
    for (int hc = 0; hc < 12; ++hc) {
        // GEMM1: H chunk rows m0..m0+15 x 64, K=192 (Wb = W1(hc))
        f32x4 acc1[4];
#pragma unroll
        for (int t = 0; t < 4; ++t) acc1[t] = (f32x4){0.f, 0.f, 0.f, 0.f};
#pragma unroll
        for (int kk = 0; kk < 6; ++kk) {
            bfrag a = *(const bfrag*)&Ab[(m0 + l16) * PBP + kk * 32 + quad * 8];
#pragma unroll
            for (int t = 0; t < 4; ++t) {
                bfrag b = *(const bfrag*)&Wb[(t * 16 + l16) * 200 + kk * 32 + quad * 8];
                acc1[t] = __builtin_amdgcn_mfma_f32_16x16x32_bf16(a, b, acc1[t], 0, 0, 0);
            }
        }
        // gelu -> Hb (own-wave rows)
#pragma unroll
        for (int t = 0; t < 4; ++t) {
            int n = t * 16 + l16;
            float bb = b_g1[hc * 64 + n];
#pragma unroll
            for (int reg = 0; reg < 4; ++reg) {
                float xv = acc1[t][reg] + bb;
                Hb[(m0 + quad * 4 + reg) * 72 + n] = f2bf(gelu_erf(xv));
            }
        }
        __syncthreads();                  // W1 reads + Hb writes done
        WRITE_CHUNK_B();                  // Wb = W2(hc)
        if (hc < 11) LOAD_CHUNK_A(W1T + (size_t)(hc + 1) * 12288);
        __syncthreads();
        // GEMM2 accumulate: 64x192, K=64 (Wb = W2(hc))
#pragma unroll
        for (int kk = 0; kk < 2; ++kk) {
            bfrag a = *(const bfrag*)&Hb[(m0 + l16) * 72 + kk * 32 + quad * 8];
#pragma unroll
            for (int t = 0; t < 12; ++t) {
                bfrag b = *(const bfrag*)&Wb[(t * 16 + l16) * 72 + kk * 32 + quad * 8];
                acc2[t] = __builtin_amdgcn_mfma_f32_16x16x32_bf16(a, b, acc2[t], 0, 0, 0);
            }
        }
        if (hc < 11) {
            __syncthreads();              // W2 reads done
            WRITE_CHUNK_A();              // Wb = W1(hc+1)
            LOAD_CHUNK_B(hc + 1);         // st = W2(hc+1)
            __syncthreads();
        }
    }
    // epilogue: product with attention output, in place
#pragma unroll
    for (int t = 0; t < 12; ++t) {
        int c = t * 16 + l16;
        float bg = b_g2[c];
#pragma unroll
        for (int reg = 0; reg < 4; ++reg) {
            size_t idx = (tok0 + m0 + quad * 4 + reg) * CDIM + c;
            a_io[idx] *= (acc2[t][reg] + bg);
        }
    }
#undef LOAD_CHUNK_A
#undef WRITE_CHUNK_A
#undef LOAD_CHUNK_B
#undef WRITE_CHUNK_B
#undef COMPUTE_V
}

// ---------------------------------------------------------------------------
// K7: fused = product @ w_proj + b (in-place), recon loss vs pb (bf16 target).
__launch_bounds__(256)
__global__ void proj_recon_kernel(const float* __restrict__ w_proj,
                                  const float* __restrict__ b_proj,
                                  const float* __restrict__ w_rec,
                                  const float* __restrict__ b_rec,
                                  const ushort* __restrict__ pb,
                                  float* __restrict__ a_io,
                                  float* __restrict__ loss) {
    __shared__ float T[64 * 196];
    __shared__ float WT[16 * 196];
    __shared__ float red[256];
    const int tid = threadIdx.x;
    const size_t m0 = (size_t)blockIdx.x * 64;
    const int tr = tid >> 5, tc = tid & 31;
    for (int i4 = tid * 4; i4 < 64 * 192; i4 += 1024) {
        float4 v = *(const float4*)&a_io[m0 * CDIM + i4];
        int r = i4 / 192, c = i4 - r * 192;
        *(float4*)&T[r * 196 + c] = v;
    }
    float facc[8][6] = {};
    for (int k0 = 0; k0 < 192; k0 += 16) {
        __syncthreads();
        for (int i4 = tid * 4; i4 < 16 * 192; i4 += 1024) {
            int kk = i4 / 192, c = i4 - kk * 192;
            float4 w = *(const float4*)&w_proj[(size_t)(k0 + kk) * CDIM + c];
            *(float4*)&WT[kk * 196 + c] = w;
        }
        __syncthreads();
#pragma unroll
        for (int k4 = 0; k4 < 16; k4 += 4) {
            float4 a[8];
#pragma unroll
            for (int i = 0; i < 8; ++i)
                a[i] = *(const float4*)&T[(tr + 8 * i) * 196 + k0 + k4];
#pragma unroll
            for (int kk = 0; kk < 4; ++kk) {
                float b[6];
#pragma unroll
                for (int j = 0; j < 6; ++j) b[j] = WT[(k4 + kk) * 196 + tc + 32 * j];
#pragma unroll
                for (int i = 0; i < 8; ++i) {
                    float av = (kk == 0) ? a[i].x : (kk == 1) ? a[i].y
                             : (kk == 2) ? a[i].z : a[i].w;
#pragma unroll
                    for (int j = 0; j < 6; ++j) facc[i][j] += av * b[j];
                }
            }
        }
    }
    __syncthreads();
#pragma unroll
    for (int j = 0; j < 6; ++j) {
        float bp = b_proj[tc + 32 * j];
#pragma unroll
        for (int i = 0; i < 8; ++i) {
            float fv = facc[i][j] + bp;
            T[(tr + 8 * i) * 196 + tc + 32 * j] = fv;
            a_io[(m0 + tr + 8 * i) * CDIM + tc + 32 * j] = fv;
        }
    }
    float racc[8][6] = {};
    for (int k0 = 0; k0 < 192; k0 += 16) {
        __syncthreads();
        for (int i4 = tid * 4; i4 < 16 * 192; i4 += 1024) {
            int kk = i4 / 192, c = i4 - kk * 192;
            float4 w = *(const float4*)&w_rec[(size_t)(k0 + kk) * CDIM + c];
            *(float4*)&WT[kk * 196 + c] = w;
        }
        __syncthreads();
#pragma unroll
        for (int k4 = 0; k4 < 16; k4 += 4) {
            float4 a[8];
#pragma unroll
            for (int i = 0; i < 8; ++i)
                a[i] = *(const float4*)&T[(tr + 8 * i) * 196 + k0 + k4];
#pragma unroll
            for (int kk = 0; kk < 4; ++kk) {
                float b[6];
#pragma unroll
                for (int j = 0; j < 6; ++j) b[j] = WT[(k4 + kk) * 196 + tc + 32 * j];
#pragma unroll
                for (int i = 0; i < 8; ++i) {
                    float av = (kk == 0) ? a[i].x : (kk == 1) ? a[i].y
                             : (kk == 2) ? a[i].z : a[i].w;
#pragma unroll
                    for (int j = 0; j < 6; ++j) racc[i][j] += av * b[j];
                }
            }
        }
    }
    float ls = 0.f;
#pragma unroll
    for (int j = 0; j < 6; ++j) {
        float br = b_rec[tc + 32 * j];
#pragma unroll
        for (int i = 0; i < 8; ++i) {
            float rv = racc[i][j] + br;
            ls += fabsf(rv - bf2f(pb[(m0 + tr + 8 * i) * PBP + tc + 32 * j]));
        }
    }
    red[tid] = ls;
    __syncthreads();
    for (int s = 128; s > 0; s >>= 1) {
        if (tid < s) red[tid] += red[tid + s];
        __syncthreads();
    }
    if (tid == 0) atomicAdd(loss, red[0] * (0.1f / (float)IMGSZ));
}

// ---------------------------------------------------------------------------
// K8: window reverse + residual.
__launch_bounds__(256)
__global__ void reverse_res_kernel(const float* __restrict__ fused,
                                   const float* __restrict__ x,
                                   float* __restrict__ out) {
    __shared__ float T[CDIM][33];
    const int tid = threadIdx.x;
    const int wt = blockIdx.x, h = blockIdx.y, b = blockIdx.z;
    const int w0 = wt * 32;
    const int l = tid & 63, jo = tid >> 6;
    for (int it = 0; it < 8; ++it) {
        int j = it * 4 + jo;
        int w = w0 + j;
        size_t token = ((size_t)(b * NWH + (h >> 3)) * NWH + (w >> 3)) * TOK
                       + ((h & 7) * 8 + (w & 7));
#pragma unroll
        for (int rep = 0; rep < 3; ++rep) {
            int c = l + rep * 64;
            T[c][j] = fused[token * CDIM + c];
        }
    }
    __syncthreads();
    const size_t rowbase = (size_t)b * CDIM * HWSZ + (size_t)h * WDIM + w0;
    for (int idx = tid; idx < CDIM * 32; idx += 256) {
        int c = idx >> 5, j = idx & 31;
        size_t gp = rowbase + (size_t)c * HWSZ + j;
        out[gp] = T[c][j] + x[gp];
    }
}

// ---------------------------------------------------------------------------
extern "C" void kernel_launch(void* const* d_in, const int* in_sizes, int n_in,
                              void* d_out, int out_size, void* d_ws, size_t ws_size,
                              hipStream_t stream) {
    const float* x      = (const float*)d_in[0];
    const float* w_pre1 = (const float*)d_in[1];
    const float* b_pre1 = (const float*)d_in[2];
    const float* w_dw   = (const float*)d_in[3];
    const float* b_dw   = (const float*)d_in[4];
    const float* ln_g   = (const float*)d_in[5];
    const float* ln_b   = (const float*)d_in[6];
    const float* w_qkv  = (const float*)d_in[7];
    const float* b_qkv  = (const float*)d_in[8];
    const float* w_proj = (const float*)d_in[9];
    const float* b_proj = (const float*)d_in[10];
    const float* w_g1   = (const float*)d_in[11];
    const float* b_g1   = (const float*)d_in[12];
    const float* w_g2   = (const float*)d_in[13];
    const float* b_g2   = (const float*)d_in[14];
    const float* w_rec  = (const float*)d_in[15];
    const float* b_rec  = (const float*)d_in[16];

    float* OutR = (float*)d_out;
    float* loss = OutR + (size_t)IMGSZ;
    float* A    = (float*)d_ws;            // 154 MB fp32 region

    // d_out layout during pipeline (front->back):
    //  [f1 fp32 full]  ->  [pb bf16 (pitch 200) ~80MB | bf16 weights ~0.8MB]
    //  final: out fp32 full + loss scalar
    ushort* pb    = (ushort*)d_out;                    // MTOK*PBP bf16
    ushort* WqkvT = pb    + (size_t)MTOK * PBP;        // 576x192 (n-major, k-contig)
    ushort* W1T   = WqkvT + 576 * 192;                 // 768x192
    ushort* W2T   = W1T   + 768 * 192;                 // 192x768
    ushort* WvT   = WqkvT + 384 * 192;                 // V rows of WqkvT (for gmlp)

    hipMemsetAsync(loss, 0, sizeof(float), stream);

    // K1: f1 = conv1x1(x) -> d_out (fp32)
    conv1x1_kernel<<<dim3(HWSZ / 64, CDIM / 64, BATCH), 256, 0, stream>>>(
        x, w_pre1, b_pre1, OutR);
    // K2: f2 = dwconv(f1) -> A
    dwconv_kernel<<<IMGSZ / 256, 256, 0, stream>>>(OutR, w_dw, b_dw, A);
    // prep bf16 weights (after f1 is dead)
    prep_weights_kernel<<<(768 * 192 + 255) / 256, 256, 0, stream>>>(
        w_qkv, w_g1, w_g2, WqkvT, W1T, W2T);
    // K3: pb = LN+partition(f2) -> d_out front (bf16, pitch PBP)
    ln_part_kernel<<<dim3(WDIM / 32, HDIM, BATCH), 256, 0, stream>>>(
        A, ln_g, ln_b, pb);
    // K4: MFMA attention -> A
    attn_mfma_kernel<<<NWIN, 256, 0, stream>>>(pb, WqkvT, b_qkv, A);
    // K5: A = attn .* gmlp(v) in place (MFMA, T14 async staging)
    gmlp_mfma_kernel<<<MTOK / 64, 256, 0, stream>>>(
        pb, WvT, b_qkv, W1T, b_g1, W2T, b_g2, A);
    // K7: A = product @ w_proj + b (in place); recon loss vs pb
    proj_recon_kernel<<<MTOK / 64, 256, 0, stream>>>(
        w_proj, b_proj, w_rec, b_rec, pb, A, loss);
    // K8: out = reverse(A) + x -> d_out
    reverse_res_kernel<<<dim3(WDIM / 32, HDIM, BATCH), 256, 0, stream>>>(
        A, x, OutR);
}

// Round 6
// 1999.352 us; speedup vs baseline: 1.3957x; 1.2164x over previous
//
#include <hip/hip_runtime.h>
#include <hip/hip_bf16.h>
#include <math.h>

// Problem constants
#define BATCH 4
#define CDIM 192
#define HDIM 224
#define WDIM 224
#define HWSZ (HDIM * WDIM)            // 50176
#define NWH 28                        // 224/8
#define NWIN (BATCH * NWH * NWH)      // 3136
#define TOK 64
#define MTOK (NWIN * TOK)             // 200704
#define HEADS 6
#define C3 (3 * CDIM)                 // 576
#define C4 (4 * CDIM)                 // 768
#define IMGSZ (BATCH * CDIM * HWSZ)   // 38535168
#define ATTN_SCALE 0.17677669529663687f
#define LN_EPS 1e-6f
#define PBP 200                        // pb row pitch (ushorts), 400 B, 16B-aligned

typedef __attribute__((ext_vector_type(8))) short bfrag;   // 8 bf16 (4 VGPRs)
typedef __attribute__((ext_vector_type(4))) float f32x4;

__device__ __forceinline__ float bf2f(unsigned short u) {
    union { unsigned int i; float f; } v; v.i = ((unsigned int)u) << 16; return v.f;
}
__device__ __forceinline__ unsigned short f2bf(float f) {
    union { unsigned int i; float f; } v; v.f = f;
    unsigned int r = (v.i + 0x7FFFu + ((v.i >> 16) & 1u)) >> 16;   // RNE
    return (unsigned short)r;
}
// exact-erf GELU via Abramowitz-Stegun 7.1.26 (|erf err| <= 1.5e-7)
__device__ __forceinline__ float gelu_erf(float x) {
    float z = fabsf(x) * 0.70710678118654752f;
    float t = __fdividef(1.0f, 1.0f + 0.3275911f * z);
    float poly = t * (0.254829592f + t * (-0.284496736f +
                 t * (1.421413741f + t * (-1.453152027f + t * 1.061405429f))));
    float erfv = 1.0f - poly * __expf(-z * z);
    erfv = (x < 0.f) ? -erfv : erfv;
    return 0.5f * x * (1.0f + erfv);
}
// async global->LDS, 16B per lane; LDS dest = uniform base + lane*16 (HW)
__device__ __forceinline__ void gload16(void* lds, const void* g) {
    __builtin_amdgcn_global_load_lds(
        (const __attribute__((address_space(1))) void*)g,
        (__attribute__((address_space(3))) void*)lds, 16, 0, 0);
}

// ---------------------------------------------------------------------------
// Prep: transpose+convert weights to bf16 (n-major, k-contiguous) once/launch.
// WqkvT full 576x192 (Q rows 0..192, K rows 192..384, V rows 384..576).
// W2C is chunk-contiguous: [hc][n(192)][kloc(64)] so each hc-chunk is a
// linear 24KB block (for global_load_lds staging).
__launch_bounds__(256)
__global__ void prep_weights_kernel(const float* __restrict__ w_qkv,
                                    const float* __restrict__ w_g1,
                                    const float* __restrict__ w_g2,
                                    ushort* __restrict__ WqkvT,
                                    ushort* __restrict__ W1T,
                                    ushort* __restrict__ W2C) {
    int idx = blockIdx.x * 256 + threadIdx.x;
    if (idx < 576 * 192) {
        int n = idx / 192, k = idx % 192;
        WqkvT[idx] = f2bf(w_qkv[(size_t)k * C3 + n]);
    }
    if (idx < 768 * 192) {
        int n = idx / 192, k = idx % 192;
        W1T[idx] = f2bf(w_g1[(size_t)k * C4 + n]);
    }
    if (idx < 192 * 768) {
        int hc = idx / 12288, rem = idx % 12288;
        int n = rem / 64, kloc = rem & 63;
        W2C[idx] = f2bf(w_g2[(size_t)(hc * 64 + kloc) * CDIM + n]);
    }
}

// ---------------------------------------------------------------------------
// K1: 1x1 conv == per-batch GEMM (fp32)
__launch_bounds__(256)
__global__ void conv1x1_kernel(const float* __restrict__ x,
                               const float* __restrict__ w1,
                               const float* __restrict__ b1,
                               float* __restrict__ f1) {
    __shared__ __align__(16) float As[16][68];
    __shared__ __align__(16) float Bs[16][64];
    const int tid = threadIdx.x;
    const int p0 = blockIdx.x * 64;
    const int m0 = blockIdx.y * 64;
    const int b  = blockIdx.z;
    const int tm = tid >> 4, tn = tid & 15;
    const int mload = tid >> 2, kload = (tid & 3) * 4;
    const int kw = tid >> 4, nw = (tid & 15) * 4;
    float acc[4][4] = {};
    const float* xb = x + (size_t)b * CDIM * HWSZ;
    for (int k0 = 0; k0 < CDIM; k0 += 16) {
        float4 av = *(const float4*)&w1[(size_t)(m0 + mload) * CDIM + k0 + kload];
        float4 bv = *(const float4*)&xb[(size_t)(k0 + kw) * HWSZ + p0 + nw];
        __syncthreads();
        As[kload + 0][mload] = av.x;
        As[kload + 1][mload] = av.y;
        As[kload + 2][mload] = av.z;
        As[kload + 3][mload] = av.w;
        *(float4*)&Bs[kw][nw] = bv;
        __syncthreads();
#pragma unroll
        for (int kk = 0; kk < 16; ++kk) {
            float a[4], bb[4];
            *(float4*)a  = *(const float4*)&As[kk][tm * 4];
            *(float4*)bb = *(const float4*)&Bs[kk][tn * 4];
#pragma unroll
            for (int i = 0; i < 4; ++i)
#pragma unroll
                for (int j = 0; j < 4; ++j) acc[i][j] += a[i] * bb[j];
        }
    }
    float* outb = f1 + (size_t)b * CDIM * HWSZ;
#pragma unroll
    for (int i = 0; i < 4; ++i) {
        int m = m0 + tm * 4 + i;
        float bias = b1[m];
        float4 o = make_float4(acc[i][0] + bias, acc[i][1] + bias,
                               acc[i][2] + bias, acc[i][3] + bias);
        *(float4*)&outb[(size_t)m * HWSZ + p0 + tn * 4] = o;
    }
}

// ---------------------------------------------------------------------------
// K2: depthwise 3x3 SAME, NCHW.
__launch_bounds__(256)
__global__ void dwconv_kernel(const float* __restrict__ f1,
                              const float* __restrict__ w_dw,
                              const float* __restrict__ b_dw,
                              float* __restrict__ f2) {
    unsigned int idx = blockIdx.x * 256u + threadIdx.x;
    int w = idx % WDIM;
    unsigned int r = idx / WDIM;
    int h = r % HDIM;
    unsigned int bc = r / HDIM;
    int c = bc % CDIM;
    const float* base = f1 + (size_t)bc * HWSZ;
    const float* wd = w_dw + c * 9;
    float acc = b_dw[c];
#pragma unroll
    for (int ky = 0; ky < 3; ++ky) {
        int hy = h + ky - 1;
        if (hy < 0 || hy >= HDIM) continue;
#pragma unroll
        for (int kx = 0; kx < 3; ++kx) {
            int wx = w + kx - 1;
            if (wx < 0 || wx >= WDIM) continue;
            acc += base[hy * WDIM + wx] * wd[ky * 3 + kx];
        }
    }
    f2[idx] = acc;
}

// ---------------------------------------------------------------------------
// K3: LayerNorm over C + window partition -> token-major pb[M][PBP] (bf16).
__launch_bounds__(256)
__global__ void ln_part_kernel(const float* __restrict__ f2,
                               const float* __restrict__ ln_g,
                               const float* __restrict__ ln_b,
                               ushort* __restrict__ pb) {
    __shared__ float T[CDIM][33];
    __shared__ float Rs[8][32], Rs2[8][32];
    __shared__ float Mu[32], Rsig[32];
    const int tid = threadIdx.x;
    const int wt = blockIdx.x, h = blockIdx.y, b = blockIdx.z;
    const int w0 = wt * 32;
    const size_t rowbase = (size_t)b * CDIM * HWSZ + (size_t)h * WDIM + w0;
    for (int idx = tid; idx < CDIM * 32; idx += 256) {
        int c = idx >> 5, j = idx & 31;
        T[c][j] = f2[rowbase + (size_t)c * HWSZ + j];
    }
    __syncthreads();
    {
        int j = tid & 31, q = tid >> 5;
        float s = 0.f, s2 = 0.f;
#pragma unroll
        for (int i = 0; i < 24; ++i) {
            float v = T[q * 24 + i][j];
            s += v; s2 += v * v;
        }
        Rs[q][j] = s; Rs2[q][j] = s2;
    }
    __syncthreads();
    if (tid < 32) {
        float s = 0.f, s2 = 0.f;
#pragma unroll
        for (int q = 0; q < 8; ++q) { s += Rs[q][tid]; s2 += Rs2[q][tid]; }
        float mu = s * (1.0f / CDIM);
        float var = s2 * (1.0f / CDIM) - mu * mu;
        Mu[tid] = mu;
        Rsig[tid] = rsqrtf(var + LN_EPS);
    }
    __syncthreads();
    const int l = tid & 63;
    const int jo = tid >> 6;
    for (int it = 0; it < 8; ++it) {
        int j = it * 4 + jo;
        int w = w0 + j;
        size_t token = ((size_t)(b * NWH + (h >> 3)) * NWH + (w >> 3)) * TOK
                       + ((h & 7) * 8 + (w & 7));
        float mu = Mu[j], rs = Rsig[j];
#pragma unroll
        for (int rep = 0; rep < 3; ++rep) {
            int c = l + rep * 64;
            pb[token * PBP + c] = f2bf((T[c][j] - mu) * rs * ln_g[c] + ln_b[c]);
        }
    }
}

// ---------------------------------------------------------------------------
// K4: MFMA attention. 1 window (64 tokens) per block, 4 waves.
// Per head: QKV GEMM (64x96, K=192, B-frags direct from global bf16 WqkvT),
// S = Q.K^T (MFMA, K=32), in-register softmax (16-lane shfl reduce),
// O = P.V^T (MFMA, K=64) -> oa fp32.
__launch_bounds__(256)
__global__ void attn_mfma_kernel(const ushort* __restrict__ pb,
                                 const ushort* __restrict__ WqkvT,
                                 const float* __restrict__ b_qkv,
                                 float* __restrict__ oa) {
    __shared__ __align__(16) ushort Pt[64 * PBP];    // 25600 B p tile, k-contig
    __shared__ __align__(16) ushort Qb[64 * 40];     //  5120 B Q (scale folded)
    __shared__ __align__(16) ushort Kb[64 * 40];     //  5120 B K
    __shared__ __align__(16) ushort Vt[32 * 72];     //  4608 B V^T (d rows, token-contig)
    __shared__ __align__(16) ushort Pbf[64 * 72];    //  9216 B softmax(P) bf16
    const int tid = threadIdx.x;
    const int lane = tid & 63, wave = tid >> 6;
    const int quad = lane >> 4, l16 = lane & 15;
    const int m0 = wave * 16;
    const size_t tok0 = (size_t)blockIdx.x * 64;

    // stage p tile: pure linear copy (pb pitch == Pt pitch == PBP)
    {
        const ushort* src = pb + tok0 * PBP;
        for (int i = tid * 8; i < 64 * PBP; i += 2048)
            *(uint4*)&Pt[i] = *(const uint4*)&src[i];
    }
    __syncthreads();

    for (int h = 0; h < HEADS; ++h) {
        // ---- QKV GEMM for this head: rows m0..m0+16 x 96 cols (Q|K|V) ----
        f32x4 acc[6];
#pragma unroll
        for (int t = 0; t < 6; ++t) acc[t] = (f32x4){0.f, 0.f, 0.f, 0.f};
#pragma unroll
        for (int kk = 0; kk < 6; ++kk) {
            bfrag a = *(const bfrag*)&Pt[(m0 + l16) * PBP + kk * 32 + quad * 8];
#pragma unroll
            for (int t = 0; t < 6; ++t) {
                const int nrow = (t < 2) ? (h * 32 + t * 16 + l16)
                               : (t < 4) ? (192 + h * 32 + (t - 2) * 16 + l16)
                                         : (384 + h * 32 + (t - 4) * 16 + l16);
                bfrag b = *(const bfrag*)&WqkvT[(size_t)nrow * 192 + kk * 32 + quad * 8];
                acc[t] = __builtin_amdgcn_mfma_f32_16x16x32_bf16(a, b, acc[t], 0, 0, 0);
            }
        }
        // write Q (scale folded), K, V^T to LDS
#pragma unroll
        for (int t = 0; t < 2; ++t) {
            float bq = b_qkv[h * 32 + t * 16 + l16];
            float bk = b_qkv[192 + h * 32 + t * 16 + l16];
            float bv = b_qkv[384 + h * 32 + t * 16 + l16];
#pragma unroll
            for (int reg = 0; reg < 4; ++reg) {
                int row = m0 + quad * 4 + reg;
                Qb[row * 40 + t * 16 + l16] = f2bf((acc[t][reg] + bq) * ATTN_SCALE);
                Kb[row * 40 + t * 16 + l16] = f2bf(acc[t + 2][reg] + bk);
                Vt[(t * 16 + l16) * 72 + row] = f2bf(acc[t + 4][reg] + bv);
            }
        }
        __syncthreads();

        // ---- S = Q.K^T (64x64, K=32): 4 col-tiles, 1 MFMA each ----
        f32x4 s[4];
        {
            bfrag aq = *(const bfrag*)&Qb[(m0 + l16) * 40 + quad * 8];
#pragma unroll
            for (int t = 0; t < 4; ++t) {
                bfrag b = *(const bfrag*)&Kb[(t * 16 + l16) * 40 + quad * 8];
                s[t] = __builtin_amdgcn_mfma_f32_16x16x32_bf16(
                    aq, b, (f32x4){0.f, 0.f, 0.f, 0.f}, 0, 0, 0);
            }
        }
        // ---- softmax per row (row = m0+quad*4+reg; 64 cols in 16 lanes x 4 tiles)
#pragma unroll
        for (int reg = 0; reg < 4; ++reg) {
            float mx = fmaxf(fmaxf(s[0][reg], s[1][reg]), fmaxf(s[2][reg], s[3][reg]));
            mx = fmaxf(mx, __shfl_xor(mx, 1));
            mx = fmaxf(mx, __shfl_xor(mx, 2));
            mx = fmaxf(mx, __shfl_xor(mx, 4));
            mx = fmaxf(mx, __shfl_xor(mx, 8));
            float e[4], sum = 0.f;
#pragma unroll
            for (int t = 0; t < 4; ++t) { e[t] = __expf(s[t][reg] - mx); sum += e[t]; }
            sum += __shfl_xor(sum, 1);
            sum += __shfl_xor(sum, 2);
            sum += __shfl_xor(sum, 4);
            sum += __shfl_xor(sum, 8);
            float inv = 1.0f / sum;
            int row = m0 + quad * 4 + reg;
#pragma unroll
            for (int t = 0; t < 4; ++t)
                Pbf[row * 72 + t * 16 + l16] = f2bf(e[t] * inv);
        }
        __syncthreads();

        // ---- O = P.V (64x32, K=64): 2 col-tiles x 2 k-steps ----
        f32x4 o[2];
        o[0] = (f32x4){0.f, 0.f, 0.f, 0.f};
        o[1] = (f32x4){0.f, 0.f, 0.f, 0.f};
#pragma unroll
        for (int kk = 0; kk < 2; ++kk) {
            bfrag a = *(const bfrag*)&Pbf[(m0 + l16) * 72 + kk * 32 + quad * 8];
#pragma unroll
            for (int t = 0; t < 2; ++t) {
                bfrag b = *(const bfrag*)&Vt[(t * 16 + l16) * 72 + kk * 32 + quad * 8];
                o[t] = __builtin_amdgcn_mfma_f32_16x16x32_bf16(a, b, o[t], 0, 0, 0);
            }
        }
#pragma unroll
        for (int t = 0; t < 2; ++t) {
            int col = h * 32 + t * 16 + l16;
#pragma unroll
            for (int reg = 0; reg < 4; ++reg) {
                int row = m0 + quad * 4 + reg;
                oa[(tok0 + row) * (size_t)CDIM + col] = o[t][reg];
            }
        }
        __syncthreads();   // protect Qb/Kb/Vt/Pbf before next head's writes
    }
}

// ---------------------------------------------------------------------------
// K5: MFMA GMLP with global_load_lds weight staging. Block = 64 tokens, 4 waves.
// Weight chunks (24KB) land in a LINEAR LDS buffer via gload_lds; bank
// conflicts on the B-fragment reads are fixed by XOR-swizzle applied on BOTH
// sides (rule 21): inverse-swizzled per-lane GLOBAL source + swizzled read.
// v = p@Wv+b; 12 hidden chunks: GEMM1 -> gelu -> GEMM2 acc.
// Epilogue: a_io *= (g + b_g2).
__launch_bounds__(256)
__global__ void gmlp_mfma_kernel(const ushort* __restrict__ pb,
                                 const ushort* __restrict__ WvT,
                                 const float* __restrict__ b_qkv,
                                 const ushort* __restrict__ W1T,
                                 const float* __restrict__ b_g1,
                                 const ushort* __restrict__ W2C,
                                 const float* __restrict__ b_g2,
                                 float* __restrict__ a_io) {
    __shared__ __align__(16) ushort Ab[64 * PBP];   // 25600 B: p tile then V
    __shared__ __align__(16) ushort Wb[12288];      // 24576 B linear weight chunk
    __shared__ __align__(16) ushort Hb[64 * 72];    //  9216 B gelu hidden chunk
    const int tid = threadIdx.x;
    const int lane = tid & 63, wave = tid >> 6;
    const int quad = lane >> 4, l16 = lane & 15;
    const int m0 = wave * 16;
    const int sw = (l16 & 7) << 3;      // read-side XOR swizzle (ushort units)
    const size_t tok0 = (size_t)blockIdx.x * 64;

    // per-thread inverse-swizzled source byte offsets within a 24KB chunk.
    // LDS byte P = (wave*6+c)*1024 + lane*16 receives global chunk byte src[c].
    int srcA[6], srcB[6], dst6[6];
#pragma unroll
    for (int c = 0; c < 6; ++c) {
        int P = (wave * 6 + c) * 1024 + lane * 16;
        dst6[c] = (wave * 6 + c) * 1024;            // wave-uniform LDS base
        int rA = P / 384;                           // A-type: 384B rows (64x192)
        int mA = P - rA * 384;
        srcA[c] = rA * 384 + (mA ^ ((rA & 7) << 4));
        srcB[c] = P ^ (((P >> 7) & 7) << 4);        // B-type: 128B rows (192x64)
    }
    char* WbB = (char*)Wb;
    char* AbB = (char*)Ab;

#define ISSUE_W(SRC, OFFS)                                                    \
    _Pragma("unroll")                                                         \
    for (int c = 0; c < 6; ++c)                                               \
        gload16(WbB + dst6[c], (const char*)(SRC) + OFFS[c]);

    // stage Ab (linear gload) + issue Wv chunk 0
    {
        const char* src = (const char*)(pb + tok0 * PBP);
#pragma unroll
        for (int c = 0; c < 6; ++c)
            gload16(AbB + dst6[c], src + dst6[c] + lane * 16);
        if (wave == 0) gload16(AbB + 24576, src + 24576 + lane * 16);
    }
    ISSUE_W(WvT, srcA);
    __syncthreads();                      // drain: Ab + Wv(0) ready

    f32x4 vacc[12];
#pragma unroll
    for (int i = 0; i < 12; ++i) vacc[i] = (f32x4){0.f, 0.f, 0.f, 0.f};

    // 64x64 tile, K=192: A rows m0..m0+15 from Ab, B rows from swizzled Wb
#define COMPUTE_K192(ACC, BASEI)                                              \
    _Pragma("unroll")                                                         \
    for (int kk = 0; kk < 6; ++kk) {                                          \
        bfrag a = *(const bfrag*)&Ab[(m0 + l16) * PBP + kk * 32 + quad * 8];  \
        _Pragma("unroll")                                                     \
        for (int t = 0; t < 4; ++t) {                                         \
            bfrag b = *(const bfrag*)&Wb[(t * 16 + l16) * 192                 \
                                         + ((kk * 32 + quad * 8) ^ sw)];      \
            ACC[(BASEI) + t] = __builtin_amdgcn_mfma_f32_16x16x32_bf16(       \
                a, b, ACC[(BASEI) + t], 0, 0, 0);                             \
        }                                                                     \
    }

    COMPUTE_K192(vacc, 0);
    __syncthreads();                      // Wv(0) reads done
    ISSUE_W((const char*)WvT + 24576, srcA);
    __syncthreads();                      // Wv(1) ready
    COMPUTE_K192(vacc, 4);
    __syncthreads();
    ISSUE_W((const char*)WvT + 49152, srcA);
    __syncthreads();                      // Wv(2) ready
    COMPUTE_K192(vacc, 8);
    // write V (bf16) into this wave's own rows of Ab (wave-private)
#pragma unroll
    for (int i = 0; i < 12; ++i) {
        int n = i * 16 + l16;
        float bias = b_qkv[384 + n];
#pragma unroll
        for (int reg = 0; reg < 4; ++reg) {
            int r = m0 + quad * 4 + reg;
            Ab[r * PBP + n] = f2bf(vacc[i][reg] + bias);
        }
    }
    __syncthreads();                      // Wv(2) reads done
    ISSUE_W(W1T, srcA);
    __syncthreads();                      // W1(0) ready

    // ---- hidden loop: 12 chunks of 64 hidden cols ----
    f32x4 acc2[12];
#pragma unroll
    for (int i = 0; i < 12; ++i) acc2[i] = (f32x4){0.f, 0.f, 0.f, 0.f};
    for (int hc = 0; hc < 12; ++hc) {
        // GEMM1: H chunk rows m0..m0+15 x 64, K=192 (Wb = W1(hc))
        f32x4 acc1[4];
#pragma unroll
        for (int t = 0; t < 4; ++t) acc1[t] = (f32x4){0.f, 0.f, 0.f, 0.f};
        COMPUTE_K192(acc1, 0);
        // gelu -> Hb (own-wave rows)
#pragma unroll
        for (int t = 0; t < 4; ++t) {
            int n = t * 16 + l16;
            float bb = b_g1[hc * 64 + n];
#pragma unroll
            for (int reg = 0; reg < 4; ++reg) {
                float xv = acc1[t][reg] + bb;
                Hb[(m0 + quad * 4 + reg) * 72 + n] = f2bf(gelu_erf(xv));
            }
        }
        __syncthreads();                  // W1 reads done
        ISSUE_W((const char*)W2C + (size_t)hc * 24576, srcB);
        __syncthreads();                  // W2(hc) ready
        // GEMM2 accumulate: 64x192, K=64 (Wb = W2C(hc), 128B rows)
#pragma unroll
        for (int kk = 0; kk < 2; ++kk) {
            bfrag a = *(const bfrag*)&Hb[(m0 + l16) * 72 + kk * 32 + quad * 8];
#pragma unroll
            for (int t = 0; t < 12; ++t) {
                bfrag b = *(const bfrag*)&Wb[(t * 16 + l16) * 64
                                             + ((kk * 32 + quad * 8) ^ sw)];
                acc2[t] = __builtin_amdgcn_mfma_f32_16x16x32_bf16(a, b, acc2[t], 0, 0, 0);
            }
        }
        if (hc < 11) {
            __syncthreads();              // W2 reads done
            ISSUE_W((const char*)W1T + (size_t)(hc + 1) * 24576, srcA);
            __syncthreads();              // W1(hc+1) ready
        }
    }
    // epilogue: product with attention output, in place
#pragma unroll
    for (int t = 0; t < 12; ++t) {
        int c = t * 16 + l16;
        float bg = b_g2[c];
#pragma unroll
        for (int reg = 0; reg < 4; ++reg) {
            size_t idx = (tok0 + m0 + quad * 4 + reg) * CDIM + c;
            a_io[idx] *= (acc2[t][reg] + bg);
        }
    }
#undef ISSUE_W
#undef COMPUTE_K192
}

// ---------------------------------------------------------------------------
// K7: fused = product @ w_proj + b (in-place), recon loss vs pb (bf16 target).
__launch_bounds__(256)
__global__ void proj_recon_kernel(const float* __restrict__ w_proj,
                                  const float* __restrict__ b_proj,
                                  const float* __restrict__ w_rec,
                                  const float* __restrict__ b_rec,
                                  const ushort* __restrict__ pb,
                                  float* __restrict__ a_io,
                                  float* __restrict__ loss) {
    __shared__ float T[64 * 196];
    __shared__ float WT[16 * 196];
    __shared__ float red[256];
    const int tid = threadIdx.x;
    const size_t m0 = (size_t)blockIdx.x * 64;
    const int tr = tid >> 5, tc = tid & 31;
    for (int i4 = tid * 4; i4 < 64 * 192; i4 += 1024) {
        float4 v = *(const float4*)&a_io[m0 * CDIM + i4];
        int r = i4 / 192, c = i4 - r * 192;
        *(float4*)&T[r * 196 + c] = v;
    }
    float facc[8][6] = {};
    for (int k0 = 0; k0 < 192; k0 += 16) {
        __syncthreads();
        for (int i4 = tid * 4; i4 < 16 * 192; i4 += 1024) {
            int kk = i4 / 192, c = i4 - kk * 192;
            float4 w = *(const float4*)&w_proj[(size_t)(k0 + kk) * CDIM + c];
            *(float4*)&WT[kk * 196 + c] = w;
        }
        __syncthreads();
#pragma unroll
        for (int k4 = 0; k4 < 16; k4 += 4) {
            float4 a[8];
#pragma unroll
            for (int i = 0; i < 8; ++i)
                a[i] = *(const float4*)&T[(tr + 8 * i) * 196 + k0 + k4];
#pragma unroll
            for (int kk = 0; kk < 4; ++kk) {
                float b[6];
#pragma unroll
                for (int j = 0; j < 6; ++j) b[j] = WT[(k4 + kk) * 196 + tc + 32 * j];
#pragma unroll
                for (int i = 0; i < 8; ++i) {
                    float av = (kk == 0) ? a[i].x : (kk == 1) ? a[i].y
                             : (kk == 2) ? a[i].z : a[i].w;
#pragma unroll
                    for (int j = 0; j < 6; ++j) facc[i][j] += av * b[j];
                }
            }
        }
    }
    __syncthreads();
#pragma unroll
    for (int j = 0; j < 6; ++j) {
        float bp = b_proj[tc + 32 * j];
#pragma unroll
        for (int i = 0; i < 8; ++i) {
            float fv = facc[i][j] + bp;
            T[(tr + 8 * i) * 196 + tc + 32 * j] = fv;
            a_io[(m0 + tr + 8 * i) * CDIM + tc + 32 * j] = fv;
        }
    }
    float racc[8][6] = {};
    for (int k0 = 0; k0 < 192; k0 += 16) {
        __syncthreads();
        for (int i4 = tid * 4; i4 < 16 * 192; i4 += 1024) {
            int kk = i4 / 192, c = i4 - kk * 192;
            float4 w = *(const float4*)&w_rec[(size_t)(k0 + kk) * CDIM + c];
            *(float4*)&WT[kk * 196 + c] = w;
        }
        __syncthreads();
#pragma unroll
        for (int k4 = 0; k4 < 16; k4 += 4) {
            float4 a[8];
#pragma unroll
            for (int i = 0; i < 8; ++i)
                a[i] = *(const float4*)&T[(tr + 8 * i) * 196 + k0 + k4];
#pragma unroll
            for (int kk = 0; kk < 4; ++kk) {
                float b[6];
#pragma unroll
                for (int j = 0; j < 6; ++j) b[j] = WT[(k4 + kk) * 196 + tc + 32 * j];
#pragma unroll
                for (int i = 0; i < 8; ++i) {
                    float av = (kk == 0) ? a[i].x : (kk == 1) ? a[i].y
                             : (kk == 2) ? a[i].z : a[i].w;
#pragma unroll
                    for (int j = 0; j < 6; ++j) racc[i][j] += av * b[j];
                }
            }
        }
    }
    float ls = 0.f;
#pragma unroll
    for (int j = 0; j < 6; ++j) {
        float br = b_rec[tc + 32 * j];
#pragma unroll
        for (int i = 0; i < 8; ++i) {
            float rv = racc[i][j] + br;
            ls += fabsf(rv - bf2f(pb[(m0 + tr + 8 * i) * PBP + tc + 32 * j]));
        }
    }
    red[tid] = ls;
    __syncthreads();
    for (int s = 128; s > 0; s >>= 1) {
        if (tid < s) red[tid] += red[tid + s];
        __syncthreads();
    }
    if (tid == 0) atomicAdd(loss, red[0] * (0.1f / (float)IMGSZ));
}

// ---------------------------------------------------------------------------
// K8: window reverse + residual.
__launch_bounds__(256)
__global__ void reverse_res_kernel(const float* __restrict__ fused,
                                   const float* __restrict__ x,
                                   float* __restrict__ out) {
    __shared__ float T[CDIM][33];
    const int tid = threadIdx.x;
    const int wt = blockIdx.x, h = blockIdx.y, b = blockIdx.z;
    const int w0 = wt * 32;
    const int l = tid & 63, jo = tid >> 6;
    for (int it = 0; it < 8; ++it) {
        int j = it * 4 + jo;
        int w = w0 + j;
        size_t token = ((size_t)(b * NWH + (h >> 3)) * NWH + (w >> 3)) * TOK
                       + ((h & 7) * 8 + (w & 7));
#pragma unroll
        for (int rep = 0; rep < 3; ++rep) {
            int c = l + rep * 64;
            T[c][j] = fused[token * CDIM + c];
        }
    }
    __syncthreads();
    const size_t rowbase = (size_t)b * CDIM * HWSZ + (size_t)h * WDIM + w0;
    for (int idx = tid; idx < CDIM * 32; idx += 256) {
        int c = idx >> 5, j = idx & 31;
        size_t gp = rowbase + (size_t)c * HWSZ + j;
        out[gp] = T[c][j] + x[gp];
    }
}

// ---------------------------------------------------------------------------
extern "C" void kernel_launch(void* const* d_in, const int* in_sizes, int n_in,
                              void* d_out, int out_size, void* d_ws, size_t ws_size,
                              hipStream_t stream) {
    const float* x      = (const float*)d_in[0];
    const float* w_pre1 = (const float*)d_in[1];
    const float* b_pre1 = (const float*)d_in[2];
    const float* w_dw   = (const float*)d_in[3];
    const float* b_dw   = (const float*)d_in[4];
    const float* ln_g   = (const float*)d_in[5];
    const float* ln_b   = (const float*)d_in[6];
    const float* w_qkv  = (const float*)d_in[7];
    const float* b_qkv  = (const float*)d_in[8];
    const float* w_proj = (const float*)d_in[9];
    const float* b_proj = (const float*)d_in[10];
    const float* w_g1   = (const float*)d_in[11];
    const float* b_g1   = (const float*)d_in[12];
    const float* w_g2   = (const float*)d_in[13];
    const float* b_g2   = (const float*)d_in[14];
    const float* w_rec  = (const float*)d_in[15];
    const float* b_rec  = (const float*)d_in[16];

    float* OutR = (float*)d_out;
    float* loss = OutR + (size_t)IMGSZ;
    float* A    = (float*)d_ws;            // 154 MB fp32 region

    // d_out layout during pipeline (front->back):
    //  [f1 fp32 full]  ->  [pb bf16 (pitch 200) ~80MB | bf16 weights ~0.8MB]
    //  final: out fp32 full + loss scalar
    ushort* pb    = (ushort*)d_out;                    // MTOK*PBP bf16
    ushort* WqkvT = pb    + (size_t)MTOK * PBP;        // 576x192 (n-major, k-contig)
    ushort* W1T   = WqkvT + 576 * 192;                 // 768x192
    ushort* W2C   = W1T   + 768 * 192;                 // [12][192][64] chunk-contig
    ushort* WvT   = WqkvT + 384 * 192;                 // V rows of WqkvT (for gmlp)

    hipMemsetAsync(loss, 0, sizeof(float), stream);

    // K1: f1 = conv1x1(x) -> d_out (fp32)
    conv1x1_kernel<<<dim3(HWSZ / 64, CDIM / 64, BATCH), 256, 0, stream>>>(
        x, w_pre1, b_pre1, OutR);
    // K2: f2 = dwconv(f1) -> A
    dwconv_kernel<<<IMGSZ / 256, 256, 0, stream>>>(OutR, w_dw, b_dw, A);
    // prep bf16 weights (after f1 is dead)
    prep_weights_kernel<<<(768 * 192 + 255) / 256, 256, 0, stream>>>(
        w_qkv, w_g1, w_g2, WqkvT, W1T, W2C);
    // K3: pb = LN+partition(f2) -> d_out front (bf16, pitch PBP)
    ln_part_kernel<<<dim3(WDIM / 32, HDIM, BATCH), 256, 0, stream>>>(
        A, ln_g, ln_b, pb);
    // K4: MFMA attention -> A
    attn_mfma_kernel<<<NWIN, 256, 0, stream>>>(pb, WqkvT, b_qkv, A);
    // K5: A = attn .* gmlp(v) in place (MFMA, gload_lds staging)
    gmlp_mfma_kernel<<<MTOK / 64, 256, 0, stream>>>(
        pb, WvT, b_qkv, W1T, b_g1, W2C, b_g2, A);
    // K7: A = product @ w_proj + b (in place); recon loss vs pb
    proj_recon_kernel<<<MTOK / 64, 256, 0, stream>>>(
        w_proj, b_proj, w_rec, b_rec, pb, A, loss);
    // K8: out = reverse(A) + x -> d_out
    reverse_res_kernel<<<dim3(WDIM / 32, HDIM, BATCH), 256, 0, stream>>>(
        A, x, OutR);
}

// Round 7
// 1539.235 us; speedup vs baseline: 1.8129x; 1.2989x over previous
//
#include <hip/hip_runtime.h>
#include <hip/hip_bf16.h>
#include <math.h>

// Problem constants
#define BATCH 4
#define CDIM 192
#define HDIM 224
#define WDIM 224
#define HWSZ (HDIM * WDIM)            // 50176
#define NWH 28                        // 224/8
#define NWIN (BATCH * NWH * NWH)      // 3136
#define TOK 64
#define MTOK (NWIN * TOK)             // 200704
#define HEADS 6
#define C3 (3 * CDIM)                 // 576
#define C4 (4 * CDIM)                 // 768
#define IMGSZ (BATCH * CDIM * HWSZ)   // 38535168
#define ATTN_SCALE 0.17677669529663687f
#define LN_EPS 1e-6f
#define PBP 200                        // pb row pitch (ushorts), 400 B, 16B-aligned

typedef __attribute__((ext_vector_type(8))) short bfrag;   // 8 bf16 (4 VGPRs)
typedef __attribute__((ext_vector_type(4))) float f32x4;

__device__ __forceinline__ float bf2f(unsigned short u) {
    union { unsigned int i; float f; } v; v.i = ((unsigned int)u) << 16; return v.f;
}
__device__ __forceinline__ unsigned short f2bf(float f) {
    union { unsigned int i; float f; } v; v.f = f;
    unsigned int r = (v.i + 0x7FFFu + ((v.i >> 16) & 1u)) >> 16;   // RNE
    return (unsigned short)r;
}
// exact-erf GELU via Abramowitz-Stegun 7.1.26 (|erf err| <= 1.5e-7)
__device__ __forceinline__ float gelu_erf(float x) {
    float z = fabsf(x) * 0.70710678118654752f;
    float t = __fdividef(1.0f, 1.0f + 0.3275911f * z);
    float poly = t * (0.254829592f + t * (-0.284496736f +
                 t * (1.421413741f + t * (-1.453152027f + t * 1.061405429f))));
    float erfv = 1.0f - poly * __expf(-z * z);
    erfv = (x < 0.f) ? -erfv : erfv;
    return 0.5f * x * (1.0f + erfv);
}
// async global->LDS, 16B per lane; LDS dest = uniform base + lane*16 (HW)
__device__ __forceinline__ void gload16(void* lds, const void* g) {
    __builtin_amdgcn_global_load_lds(
        (const __attribute__((address_space(1))) void*)g,
        (__attribute__((address_space(3))) void*)lds, 16, 0, 0);
}

// ---------------------------------------------------------------------------
// Prep: transpose+convert weights to bf16 (n-major, k-contiguous) once/launch.
// WqkvT full 576x192. W2C chunk-contiguous [hc][n(192)][kloc(64)].
// WpT/WrT: 192x192 n-major for proj/recon MFMA.
__launch_bounds__(256)
__global__ void prep_weights_kernel(const float* __restrict__ w_qkv,
                                    const float* __restrict__ w_g1,
                                    const float* __restrict__ w_g2,
                                    const float* __restrict__ w_proj,
                                    const float* __restrict__ w_rec,
                                    ushort* __restrict__ WqkvT,
                                    ushort* __restrict__ W1T,
                                    ushort* __restrict__ W2C,
                                    ushort* __restrict__ WpT,
                                    ushort* __restrict__ WrT) {
    int idx = blockIdx.x * 256 + threadIdx.x;
    if (idx < 576 * 192) {
        int n = idx / 192, k = idx % 192;
        WqkvT[idx] = f2bf(w_qkv[(size_t)k * C3 + n]);
    }
    if (idx < 768 * 192) {
        int n = idx / 192, k = idx % 192;
        W1T[idx] = f2bf(w_g1[(size_t)k * C4 + n]);
    }
    if (idx < 192 * 768) {
        int hc = idx / 12288, rem = idx % 12288;
        int n = rem / 64, kloc = rem & 63;
        W2C[idx] = f2bf(w_g2[(size_t)(hc * 64 + kloc) * CDIM + n]);
    }
    if (idx < 192 * 192) {
        int n = idx / 192, k = idx % 192;
        WpT[idx] = f2bf(w_proj[(size_t)k * CDIM + n]);
        WrT[idx] = f2bf(w_rec[(size_t)k * CDIM + n]);
    }
}

// ---------------------------------------------------------------------------
// K1: 1x1 conv == per-batch GEMM (fp32)
__launch_bounds__(256)
__global__ void conv1x1_kernel(const float* __restrict__ x,
                               const float* __restrict__ w1,
                               const float* __restrict__ b1,
                               float* __restrict__ f1) {
    __shared__ __align__(16) float As[16][68];
    __shared__ __align__(16) float Bs[16][64];
    const int tid = threadIdx.x;
    const int p0 = blockIdx.x * 64;
    const int m0 = blockIdx.y * 64;
    const int b  = blockIdx.z;
    const int tm = tid >> 4, tn = tid & 15;
    const int mload = tid >> 2, kload = (tid & 3) * 4;
    const int kw = tid >> 4, nw = (tid & 15) * 4;
    float acc[4][4] = {};
    const float* xb = x + (size_t)b * CDIM * HWSZ;
    for (int k0 = 0; k0 < CDIM; k0 += 16) {
        float4 av = *(const float4*)&w1[(size_t)(m0 + mload) * CDIM + k0 + kload];
        float4 bv = *(const float4*)&xb[(size_t)(k0 + kw) * HWSZ + p0 + nw];
        __syncthreads();
        As[kload + 0][mload] = av.x;
        As[kload + 1][mload] = av.y;
        As[kload + 2][mload] = av.z;
        As[kload + 3][mload] = av.w;
        *(float4*)&Bs[kw][nw] = bv;
        __syncthreads();
#pragma unroll
        for (int kk = 0; kk < 16; ++kk) {
            float a[4], bb[4];
            *(float4*)a  = *(const float4*)&As[kk][tm * 4];
            *(float4*)bb = *(const float4*)&Bs[kk][tn * 4];
#pragma unroll
            for (int i = 0; i < 4; ++i)
#pragma unroll
                for (int j = 0; j < 4; ++j) acc[i][j] += a[i] * bb[j];
        }
    }
    float* outb = f1 + (size_t)b * CDIM * HWSZ;
#pragma unroll
    for (int i = 0; i < 4; ++i) {
        int m = m0 + tm * 4 + i;
        float bias = b1[m];
        float4 o = make_float4(acc[i][0] + bias, acc[i][1] + bias,
                               acc[i][2] + bias, acc[i][3] + bias);
        *(float4*)&outb[(size_t)m * HWSZ + p0 + tn * 4] = o;
    }
}

// ---------------------------------------------------------------------------
// K2: depthwise 3x3 SAME, NCHW.
__launch_bounds__(256)
__global__ void dwconv_kernel(const float* __restrict__ f1,
                              const float* __restrict__ w_dw,
                              const float* __restrict__ b_dw,
                              float* __restrict__ f2) {
    unsigned int idx = blockIdx.x * 256u + threadIdx.x;
    int w = idx % WDIM;
    unsigned int r = idx / WDIM;
    int h = r % HDIM;
    unsigned int bc = r / HDIM;
    int c = bc % CDIM;
    const float* base = f1 + (size_t)bc * HWSZ;
    const float* wd = w_dw + c * 9;
    float acc = b_dw[c];
#pragma unroll
    for (int ky = 0; ky < 3; ++ky) {
        int hy = h + ky - 1;
        if (hy < 0 || hy >= HDIM) continue;
#pragma unroll
        for (int kx = 0; kx < 3; ++kx) {
            int wx = w + kx - 1;
            if (wx < 0 || wx >= WDIM) continue;
            acc += base[hy * WDIM + wx] * wd[ky * 3 + kx];
        }
    }
    f2[idx] = acc;
}

// ---------------------------------------------------------------------------
// K3: LayerNorm over C + window partition -> token-major pb[M][PBP] (bf16).
__launch_bounds__(256)
__global__ void ln_part_kernel(const float* __restrict__ f2,
                               const float* __restrict__ ln_g,
                               const float* __restrict__ ln_b,
                               ushort* __restrict__ pb) {
    __shared__ float T[CDIM][33];
    __shared__ float Rs[8][32], Rs2[8][32];
    __shared__ float Mu[32], Rsig[32];
    const int tid = threadIdx.x;
    const int wt = blockIdx.x, h = blockIdx.y, b = blockIdx.z;
    const int w0 = wt * 32;
    const size_t rowbase = (size_t)b * CDIM * HWSZ + (size_t)h * WDIM + w0;
    for (int idx = tid; idx < CDIM * 32; idx += 256) {
        int c = idx >> 5, j = idx & 31;
        T[c][j] = f2[rowbase + (size_t)c * HWSZ + j];
    }
    __syncthreads();
    {
        int j = tid & 31, q = tid >> 5;
        float s = 0.f, s2 = 0.f;
#pragma unroll
        for (int i = 0; i < 24; ++i) {
            float v = T[q * 24 + i][j];
            s += v; s2 += v * v;
        }
        Rs[q][j] = s; Rs2[q][j] = s2;
    }
    __syncthreads();
    if (tid < 32) {
        float s = 0.f, s2 = 0.f;
#pragma unroll
        for (int q = 0; q < 8; ++q) { s += Rs[q][tid]; s2 += Rs2[q][tid]; }
        float mu = s * (1.0f / CDIM);
        float var = s2 * (1.0f / CDIM) - mu * mu;
        Mu[tid] = mu;
        Rsig[tid] = rsqrtf(var + LN_EPS);
    }
    __syncthreads();
    const int l = tid & 63;
    const int jo = tid >> 6;
    for (int it = 0; it < 8; ++it) {
        int j = it * 4 + jo;
        int w = w0 + j;
        size_t token = ((size_t)(b * NWH + (h >> 3)) * NWH + (w >> 3)) * TOK
                       + ((h & 7) * 8 + (w & 7));
        float mu = Mu[j], rs = Rsig[j];
#pragma unroll
        for (int rep = 0; rep < 3; ++rep) {
            int c = l + rep * 64;
            pb[token * PBP + c] = f2bf((T[c][j] - mu) * rs * ln_g[c] + ln_b[c]);
        }
    }
}

// ---------------------------------------------------------------------------
// K4: MFMA attention. 1 window (64 tokens) per block, 4 waves.
__launch_bounds__(256)
__global__ void attn_mfma_kernel(const ushort* __restrict__ pb,
                                 const ushort* __restrict__ WqkvT,
                                 const float* __restrict__ b_qkv,
                                 float* __restrict__ oa) {
    __shared__ __align__(16) ushort Pt[64 * PBP];    // 25600 B p tile, k-contig
    __shared__ __align__(16) ushort Qb[64 * 40];     //  5120 B Q (scale folded)
    __shared__ __align__(16) ushort Kb[64 * 40];     //  5120 B K
    __shared__ __align__(16) ushort Vt[32 * 72];     //  4608 B V^T (d rows, token-contig)
    __shared__ __align__(16) ushort Pbf[64 * 72];    //  9216 B softmax(P) bf16
    const int tid = threadIdx.x;
    const int lane = tid & 63, wave = tid >> 6;
    const int quad = lane >> 4, l16 = lane & 15;
    const int m0 = wave * 16;
    const size_t tok0 = (size_t)blockIdx.x * 64;

    // stage p tile: pure linear copy (pb pitch == Pt pitch == PBP)
    {
        const ushort* src = pb + tok0 * PBP;
        for (int i = tid * 8; i < 64 * PBP; i += 2048)
            *(uint4*)&Pt[i] = *(const uint4*)&src[i];
    }
    __syncthreads();

    for (int h = 0; h < HEADS; ++h) {
        // ---- QKV GEMM for this head: rows m0..m0+16 x 96 cols (Q|K|V) ----
        f32x4 acc[6];
#pragma unroll
        for (int t = 0; t < 6; ++t) acc[t] = (f32x4){0.f, 0.f, 0.f, 0.f};
#pragma unroll
        for (int kk = 0; kk < 6; ++kk) {
            bfrag a = *(const bfrag*)&Pt[(m0 + l16) * PBP + kk * 32 + quad * 8];
#pragma unroll
            for (int t = 0; t < 6; ++t) {
                const int nrow = (t < 2) ? (h * 32 + t * 16 + l16)
                               : (t < 4) ? (192 + h * 32 + (t - 2) * 16 + l16)
                                         : (384 + h * 32 + (t - 4) * 16 + l16);
                bfrag b = *(const bfrag*)&WqkvT[(size_t)nrow * 192 + kk * 32 + quad * 8];
                acc[t] = __builtin_amdgcn_mfma_f32_16x16x32_bf16(a, b, acc[t], 0, 0, 0);
            }
        }
        // write Q (scale folded), K, V^T to LDS
#pragma unroll
        for (int t = 0; t < 2; ++t) {
            float bq = b_qkv[h * 32 + t * 16 + l16];
            float bk = b_qkv[192 + h * 32 + t * 16 + l16];
            float bv = b_qkv[384 + h * 32 + t * 16 + l16];
#pragma unroll
            for (int reg = 0; reg < 4; ++reg) {
                int row = m0 + quad * 4 + reg;
                Qb[row * 40 + t * 16 + l16] = f2bf((acc[t][reg] + bq) * ATTN_SCALE);
                Kb[row * 40 + t * 16 + l16] = f2bf(acc[t + 2][reg] + bk);
                Vt[(t * 16 + l16) * 72 + row] = f2bf(acc[t + 4][reg] + bv);
            }
        }
        __syncthreads();

        // ---- S = Q.K^T (64x64, K=32): 4 col-tiles, 1 MFMA each ----
        f32x4 s[4];
        {
            bfrag aq = *(const bfrag*)&Qb[(m0 + l16) * 40 + quad * 8];
#pragma unroll
            for (int t = 0; t < 4; ++t) {
                bfrag b = *(const bfrag*)&Kb[(t * 16 + l16) * 40 + quad * 8];
                s[t] = __builtin_amdgcn_mfma_f32_16x16x32_bf16(
                    aq, b, (f32x4){0.f, 0.f, 0.f, 0.f}, 0, 0, 0);
            }
        }
        // ---- softmax per row
#pragma unroll
        for (int reg = 0; reg < 4; ++reg) {
            float mx = fmaxf(fmaxf(s[0][reg], s[1][reg]), fmaxf(s[2][reg], s[3][reg]));
            mx = fmaxf(mx, __shfl_xor(mx, 1));
            mx = fmaxf(mx, __shfl_xor(mx, 2));
            mx = fmaxf(mx, __shfl_xor(mx, 4));
            mx = fmaxf(mx, __shfl_xor(mx, 8));
            float e[4], sum = 0.f;
#pragma unroll
            for (int t = 0; t < 4; ++t) { e[t] = __expf(s[t][reg] - mx); sum += e[t]; }
            sum += __shfl_xor(sum, 1);
            sum += __shfl_xor(sum, 2);
            sum += __shfl_xor(sum, 4);
            sum += __shfl_xor(sum, 8);
            float inv = 1.0f / sum;
            int row = m0 + quad * 4 + reg;
#pragma unroll
            for (int t = 0; t < 4; ++t)
                Pbf[row * 72 + t * 16 + l16] = f2bf(e[t] * inv);
        }
        __syncthreads();

        // ---- O = P.V (64x32, K=64): 2 col-tiles x 2 k-steps ----
        f32x4 o[2];
        o[0] = (f32x4){0.f, 0.f, 0.f, 0.f};
        o[1] = (f32x4){0.f, 0.f, 0.f, 0.f};
#pragma unroll
        for (int kk = 0; kk < 2; ++kk) {
            bfrag a = *(const bfrag*)&Pbf[(m0 + l16) * 72 + kk * 32 + quad * 8];
#pragma unroll
            for (int t = 0; t < 2; ++t) {
                bfrag b = *(const bfrag*)&Vt[(t * 16 + l16) * 72 + kk * 32 + quad * 8];
                o[t] = __builtin_amdgcn_mfma_f32_16x16x32_bf16(a, b, o[t], 0, 0, 0);
            }
        }
#pragma unroll
        for (int t = 0; t < 2; ++t) {
            int col = h * 32 + t * 16 + l16;
#pragma unroll
            for (int reg = 0; reg < 4; ++reg) {
                int row = m0 + quad * 4 + reg;
                oa[(tok0 + row) * (size_t)CDIM + col] = o[t][reg];
            }
        }
        __syncthreads();   // protect Qb/Kb/Vt/Pbf before next head's writes
    }
}

// ---------------------------------------------------------------------------
// K5: MFMA GMLP with global_load_lds weight staging (round-6, proven).
__launch_bounds__(256)
__global__ void gmlp_mfma_kernel(const ushort* __restrict__ pb,
                                 const ushort* __restrict__ WvT,
                                 const float* __restrict__ b_qkv,
                                 const ushort* __restrict__ W1T,
                                 const float* __restrict__ b_g1,
                                 const ushort* __restrict__ W2C,
                                 const float* __restrict__ b_g2,
                                 float* __restrict__ a_io) {
    __shared__ __align__(16) ushort Ab[64 * PBP];   // 25600 B: p tile then V
    __shared__ __align__(16) ushort Wb[12288];      // 24576 B linear weight chunk
    __shared__ __align__(16) ushort Hb[64 * 72];    //  9216 B gelu hidden chunk
    const int tid = threadIdx.x;
    const int lane = tid & 63, wave = tid >> 6;
    const int quad = lane >> 4, l16 = lane & 15;
    const int m0 = wave * 16;
    const int sw = (l16 & 7) << 3;      // read-side XOR swizzle (ushort units)
    const size_t tok0 = (size_t)blockIdx.x * 64;

    int srcA[6], srcB[6], dst6[6];
#pragma unroll
    for (int c = 0; c < 6; ++c) {
        int P = (wave * 6 + c) * 1024 + lane * 16;
        dst6[c] = (wave * 6 + c) * 1024;            // wave-uniform LDS base
        int rA = P / 384;                           // A-type: 384B rows (64x192)
        int mA = P - rA * 384;
        srcA[c] = rA * 384 + (mA ^ ((rA & 7) << 4));
        srcB[c] = P ^ (((P >> 7) & 7) << 4);        // B-type: 128B rows (192x64)
    }
    char* WbB = (char*)Wb;
    char* AbB = (char*)Ab;

#define ISSUE_W(SRC, OFFS)                                                    \
    _Pragma("unroll")                                                         \
    for (int c = 0; c < 6; ++c)                                               \
        gload16(WbB + dst6[c], (const char*)(SRC) + OFFS[c]);

    // stage Ab (linear gload) + issue Wv chunk 0
    {
        const char* src = (const char*)(pb + tok0 * PBP);
#pragma unroll
        for (int c = 0; c < 6; ++c)
            gload16(AbB + dst6[c], src + dst6[c] + lane * 16);
        if (wave == 0) gload16(AbB + 24576, src + 24576 + lane * 16);
    }
    ISSUE_W(WvT, srcA);
    __syncthreads();                      // drain: Ab + Wv(0) ready

    f32x4 vacc[12];
#pragma unroll
    for (int i = 0; i < 12; ++i) vacc[i] = (f32x4){0.f, 0.f, 0.f, 0.f};

#define COMPUTE_K192(ACC, BASEI)                                              \
    _Pragma("unroll")                                                         \
    for (int kk = 0; kk < 6; ++kk) {                                          \
        bfrag a = *(const bfrag*)&Ab[(m0 + l16) * PBP + kk * 32 + quad * 8];  \
        _Pragma("unroll")                                                     \
        for (int t = 0; t < 4; ++t) {                                         \
            bfrag b = *(const bfrag*)&Wb[(t * 16 + l16) * 192                 \
                                         + ((kk * 32 + quad * 8) ^ sw)];      \
            ACC[(BASEI) + t] = __builtin_amdgcn_mfma_f32_16x16x32_bf16(       \
                a, b, ACC[(BASEI) + t], 0, 0, 0);                             \
        }                                                                     \
    }

    COMPUTE_K192(vacc, 0);
    __syncthreads();
    ISSUE_W((const char*)WvT + 24576, srcA);
    __syncthreads();
    COMPUTE_K192(vacc, 4);
    __syncthreads();
    ISSUE_W((const char*)WvT + 49152, srcA);
    __syncthreads();
    COMPUTE_K192(vacc, 8);
    // write V (bf16) into this wave's own rows of Ab (wave-private)
#pragma unroll
    for (int i = 0; i < 12; ++i) {
        int n = i * 16 + l16;
        float bias = b_qkv[384 + n];
#pragma unroll
        for (int reg = 0; reg < 4; ++reg) {
            int r = m0 + quad * 4 + reg;
            Ab[r * PBP + n] = f2bf(vacc[i][reg] + bias);
        }
    }
    __syncthreads();
    ISSUE_W(W1T, srcA);
    __syncthreads();

    // ---- hidden loop: 12 chunks of 64 hidden cols ----
    f32x4 acc2[12];
#pragma unroll
    for (int i = 0; i < 12; ++i) acc2[i] = (f32x4){0.f, 0.f, 0.f, 0.f};
    for (int hc = 0; hc < 12; ++hc) {
        f32x4 acc1[4];
#pragma unroll
        for (int t = 0; t < 4; ++t) acc1[t] = (f32x4){0.f, 0.f, 0.f, 0.f};
        COMPUTE_K192(acc1, 0);
#pragma unroll
        for (int t = 0; t < 4; ++t) {
            int n = t * 16 + l16;
            float bb = b_g1[hc * 64 + n];
#pragma unroll
            for (int reg = 0; reg < 4; ++reg) {
                float xv = acc1[t][reg] + bb;
                Hb[(m0 + quad * 4 + reg) * 72 + n] = f2bf(gelu_erf(xv));
            }
        }
        __syncthreads();                  // W1 reads done
        ISSUE_W((const char*)W2C + (size_t)hc * 24576, srcB);
        __syncthreads();                  // W2(hc) ready
#pragma unroll
        for (int kk = 0; kk < 2; ++kk) {
            bfrag a = *(const bfrag*)&Hb[(m0 + l16) * 72 + kk * 32 + quad * 8];
#pragma unroll
            for (int t = 0; t < 12; ++t) {
                bfrag b = *(const bfrag*)&Wb[(t * 16 + l16) * 64
                                             + ((kk * 32 + quad * 8) ^ sw)];
                acc2[t] = __builtin_amdgcn_mfma_f32_16x16x32_bf16(a, b, acc2[t], 0, 0, 0);
            }
        }
        if (hc < 11) {
            __syncthreads();              // W2 reads done
            ISSUE_W((const char*)W1T + (size_t)(hc + 1) * 24576, srcA);
            __syncthreads();              // W1(hc+1) ready
        }
    }
    // epilogue: product with attention output, in place
#pragma unroll
    for (int t = 0; t < 12; ++t) {
        int c = t * 16 + l16;
        float bg = b_g2[c];
#pragma unroll
        for (int reg = 0; reg < 4; ++reg) {
            size_t idx = (tok0 + m0 + quad * 4 + reg) * CDIM + c;
            a_io[idx] *= (acc2[t][reg] + bg);
        }
    }
#undef ISSUE_W
#undef COMPUTE_K192
}

// ---------------------------------------------------------------------------
// K7: MFMA proj+recon. Block = 64 tokens, 4 waves. F = product@WpT + b_proj
// (fp32 out to a_io, bf16 into Tb wave rows); R = F@WrT + b_rec; L1 loss vs
// pb. Weights staged via gload_lds linear chunks + both-sides swizzle
// (identical pattern to gmlp K5, srcA layout).
__launch_bounds__(256)
__global__ void proj_recon_kernel(const ushort* __restrict__ WpT,
                                  const float* __restrict__ b_proj,
                                  const ushort* __restrict__ WrT,
                                  const float* __restrict__ b_rec,
                                  const ushort* __restrict__ pb,
                                  float* __restrict__ a_io,
                                  float* __restrict__ loss) {
    __shared__ __align__(16) ushort Tb[64 * PBP];   // 25600 B product/F (bf16)
    __shared__ __align__(16) ushort Wb[12288];      // 24576 B weight chunk
    __shared__ float red[256];
    const int tid = threadIdx.x;
    const int lane = tid & 63, wave = tid >> 6;
    const int quad = lane >> 4, l16 = lane & 15;
    const int m0 = wave * 16;
    const int sw = (l16 & 7) << 3;
    const size_t tok0 = (size_t)blockIdx.x * 64;

    int srcA[6], dst6[6];
#pragma unroll
    for (int c = 0; c < 6; ++c) {
        int P = (wave * 6 + c) * 1024 + lane * 16;
        dst6[c] = (wave * 6 + c) * 1024;
        int rA = P / 384;
        int mA = P - rA * 384;
        srcA[c] = rA * 384 + (mA ^ ((rA & 7) << 4));
    }
    char* WbB = (char*)Wb;

#define PR_ISSUE(SRC)                                                         \
    _Pragma("unroll")                                                         \
    for (int c = 0; c < 6; ++c)                                               \
        gload16(WbB + dst6[c], (const char*)(SRC) + srcA[c]);
#define PR_COMPUTE(ACC, BASEI)                                                \
    _Pragma("unroll")                                                         \
    for (int kk = 0; kk < 6; ++kk) {                                          \
        bfrag a = *(const bfrag*)&Tb[(m0 + l16) * PBP + kk * 32 + quad * 8];  \
        _Pragma("unroll")                                                     \
        for (int t = 0; t < 4; ++t) {                                         \
            bfrag b = *(const bfrag*)&Wb[(t * 16 + l16) * 192                 \
                                         + ((kk * 32 + quad * 8) ^ sw)];      \
            ACC[(BASEI) + t] = __builtin_amdgcn_mfma_f32_16x16x32_bf16(       \
                a, b, ACC[(BASEI) + t], 0, 0, 0);                             \
        }                                                                     \
    }

    // stage product tile fp32 -> bf16 Tb; issue Wp chunk 0
    PR_ISSUE(WpT);
    for (int i4 = tid * 4; i4 < 64 * 192; i4 += 1024) {
        float4 v = *(const float4*)&a_io[tok0 * CDIM + i4];
        int r = i4 / 192, c = i4 - r * 192;
        ushort u[4] = { f2bf(v.x), f2bf(v.y), f2bf(v.z), f2bf(v.w) };
        *(uint2*)&Tb[r * PBP + c] = *(uint2*)u;
    }
    __syncthreads();                      // Tb + Wp(0) ready

    // ---- F = product @ w_proj: 3 chunks of 64 N-cols, K=192 ----
    f32x4 facc[12];
#pragma unroll
    for (int i = 0; i < 12; ++i) facc[i] = (f32x4){0.f, 0.f, 0.f, 0.f};
    PR_COMPUTE(facc, 0);
    __syncthreads();
    PR_ISSUE((const char*)WpT + 24576);
    __syncthreads();
    PR_COMPUTE(facc, 4);
    __syncthreads();
    PR_ISSUE((const char*)WpT + 49152);
    __syncthreads();
    PR_COMPUTE(facc, 8);
    // write F: fp32 to a_io, bf16 into own-wave rows of Tb (A for recon)
#pragma unroll
    for (int i = 0; i < 12; ++i) {
        int n = i * 16 + l16;
        float bp = b_proj[n];
#pragma unroll
        for (int reg = 0; reg < 4; ++reg) {
            int r = m0 + quad * 4 + reg;
            float fv = facc[i][reg] + bp;
            a_io[(tok0 + r) * (size_t)CDIM + n] = fv;
            Tb[r * PBP + n] = f2bf(fv);
        }
    }
    __syncthreads();                      // Wp(2) reads done
    PR_ISSUE(WrT);
    __syncthreads();                      // Wr(0) ready

    // ---- R = F @ w_rec: 3 chunks ----
    f32x4 racc[12];
#pragma unroll
    for (int i = 0; i < 12; ++i) racc[i] = (f32x4){0.f, 0.f, 0.f, 0.f};
    PR_COMPUTE(racc, 0);
    __syncthreads();
    PR_ISSUE((const char*)WrT + 24576);
    __syncthreads();
    PR_COMPUTE(racc, 4);
    __syncthreads();
    PR_ISSUE((const char*)WrT + 49152);
    __syncthreads();
    PR_COMPUTE(racc, 8);

    // ---- L1 loss vs pb ----
    float ls = 0.f;
#pragma unroll
    for (int i = 0; i < 12; ++i) {
        int n = i * 16 + l16;
        float br = b_rec[n];
#pragma unroll
        for (int reg = 0; reg < 4; ++reg) {
            int r = m0 + quad * 4 + reg;
            float rv = racc[i][reg] + br;
            ls += fabsf(rv - bf2f(pb[(tok0 + r) * PBP + n]));
        }
    }
    red[tid] = ls;
    __syncthreads();
    for (int s = 128; s > 0; s >>= 1) {
        if (tid < s) red[tid] += red[tid + s];
        __syncthreads();
    }
    if (tid == 0) atomicAdd(loss, red[0] * (0.1f / (float)IMGSZ));
#undef PR_ISSUE
#undef PR_COMPUTE
}

// ---------------------------------------------------------------------------
// K8: window reverse + residual.
__launch_bounds__(256)
__global__ void reverse_res_kernel(const float* __restrict__ fused,
                                   const float* __restrict__ x,
                                   float* __restrict__ out) {
    __shared__ float T[CDIM][33];
    const int tid = threadIdx.x;
    const int wt = blockIdx.x, h = blockIdx.y, b = blockIdx.z;
    const int w0 = wt * 32;
    const int l = tid & 63, jo = tid >> 6;
    for (int it = 0; it < 8; ++it) {
        int j = it * 4 + jo;
        int w = w0 + j;
        size_t token = ((size_t)(b * NWH + (h >> 3)) * NWH + (w >> 3)) * TOK
                       + ((h & 7) * 8 + (w & 7));
#pragma unroll
        for (int rep = 0; rep < 3; ++rep) {
            int c = l + rep * 64;
            T[c][j] = fused[token * CDIM + c];
        }
    }
    __syncthreads();
    const size_t rowbase = (size_t)b * CDIM * HWSZ + (size_t)h * WDIM + w0;
    for (int idx = tid; idx < CDIM * 32; idx += 256) {
        int c = idx >> 5, j = idx & 31;
        size_t gp = rowbase + (size_t)c * HWSZ + j;
        out[gp] = T[c][j] + x[gp];
    }
}

// ---------------------------------------------------------------------------
extern "C" void kernel_launch(void* const* d_in, const int* in_sizes, int n_in,
                              void* d_out, int out_size, void* d_ws, size_t ws_size,
                              hipStream_t stream) {
    const float* x      = (const float*)d_in[0];
    const float* w_pre1 = (const float*)d_in[1];
    const float* b_pre1 = (const float*)d_in[2];
    const float* w_dw   = (const float*)d_in[3];
    const float* b_dw   = (const float*)d_in[4];
    const float* ln_g   = (const float*)d_in[5];
    const float* ln_b   = (const float*)d_in[6];
    const float* w_qkv  = (const float*)d_in[7];
    const float* b_qkv  = (const float*)d_in[8];
    const float* w_proj = (const float*)d_in[9];
    const float* b_proj = (const float*)d_in[10];
    const float* w_g1   = (const float*)d_in[11];
    const float* b_g1   = (const float*)d_in[12];
    const float* w_g2   = (const float*)d_in[13];
    const float* b_g2   = (const float*)d_in[14];
    const float* w_rec  = (const float*)d_in[15];
    const float* b_rec  = (const float*)d_in[16];

    float* OutR = (float*)d_out;
    float* loss = OutR + (size_t)IMGSZ;
    float* A    = (float*)d_ws;            // 154 MB fp32 region

    // d_out layout during pipeline (front->back):
    //  [f1 fp32 full]  ->  [pb bf16 (pitch 200) ~80MB | bf16 weights ~1MB]
    //  final: out fp32 full + loss scalar
    ushort* pb    = (ushort*)d_out;                    // MTOK*PBP bf16
    ushort* WqkvT = pb    + (size_t)MTOK * PBP;        // 576x192 (n-major, k-contig)
    ushort* W1T   = WqkvT + 576 * 192;                 // 768x192
    ushort* W2C   = W1T   + 768 * 192;                 // [12][192][64] chunk-contig
    ushort* WpT   = W2C   + 192 * 768;                 // 192x192
    ushort* WrT   = WpT   + 192 * 192;                 // 192x192
    ushort* WvT   = WqkvT + 384 * 192;                 // V rows of WqkvT (for gmlp)

    hipMemsetAsync(loss, 0, sizeof(float), stream);

    // K1: f1 = conv1x1(x) -> d_out (fp32)
    conv1x1_kernel<<<dim3(HWSZ / 64, CDIM / 64, BATCH), 256, 0, stream>>>(
        x, w_pre1, b_pre1, OutR);
    // K2: f2 = dwconv(f1) -> A
    dwconv_kernel<<<IMGSZ / 256, 256, 0, stream>>>(OutR, w_dw, b_dw, A);
    // prep bf16 weights (after f1 is dead)
    prep_weights_kernel<<<(768 * 192 + 255) / 256, 256, 0, stream>>>(
        w_qkv, w_g1, w_g2, w_proj, w_rec, WqkvT, W1T, W2C, WpT, WrT);
    // K3: pb = LN+partition(f2) -> d_out front (bf16, pitch PBP)
    ln_part_kernel<<<dim3(WDIM / 32, HDIM, BATCH), 256, 0, stream>>>(
        A, ln_g, ln_b, pb);
    // K4: MFMA attention -> A
    attn_mfma_kernel<<<NWIN, 256, 0, stream>>>(pb, WqkvT, b_qkv, A);
    // K5: A = attn .* gmlp(v) in place (MFMA, gload_lds staging)
    gmlp_mfma_kernel<<<MTOK / 64, 256, 0, stream>>>(
        pb, WvT, b_qkv, W1T, b_g1, W2C, b_g2, A);
    // K7: A = product @ w_proj + b (in place, MFMA); recon loss vs pb
    proj_recon_kernel<<<MTOK / 64, 256, 0, stream>>>(
        WpT, b_proj, WrT, b_rec, pb, A, loss);
    // K8: out = reverse(A) + x -> d_out
    reverse_res_kernel<<<dim3(WDIM / 32, HDIM, BATCH), 256, 0, stream>>>(
        A, x, OutR);
}